// Round 2
// baseline (1063.884 us; speedup 1.0000x reference)
//
#include <hip/hip_runtime.h>
#include <hip/hip_bf16.h>

// Problem constants
#define BDIM 2
#define LDIM 512
#define CDIM 576
#define HDIM 8
#define CPD  128
#define DK3  24
#define INV_DIV 0.117851130197757920f   // 1/sqrt(72)

// Workspace layout (floats). Total = 32,899,072 floats = 125.5 MiB required in d_ws.
static constexpr size_t OFF_Q    = 0;                       // [B,3,H,L,24] 589824
static constexpr size_t OFF_K    = 589824;
static constexpr size_t OFF_V    = 1179648;
static constexpr size_t OFF_G    = 1769472;
static constexpr size_t OFF_BIAS = 2359296;                 // [B,H,L,L] 4194304 ; reused as gq [B,L,L,H] after k_qkmat
static constexpr size_t OFF_ORI  = OFF_BIAS + 4194304;      // [B,3,H,L,L] 12582912
static constexpr size_t OFF_QK   = OFF_ORI + 12582912;      // [B,3,H,L,L] 12582912
static constexpr size_t OFF_H    = OFF_QK + 12582912;       // [B*L,576]   589824

__device__ __forceinline__ float gelu_exact(float v) {
    return 0.5f * v * (1.f + erff(v * 0.70710678118654752f));
}

// ---------------------------------------------------------------------------
// K1: LN(x) + q/k/v/gate projections.  1 block = 4 rows (b,l). grid=256.
// ---------------------------------------------------------------------------
__global__ __launch_bounds__(256) void k_ln_proj(
    const float* __restrict__ x, const float* __restrict__ ln1w, const float* __restrict__ ln1b,
    const float* __restrict__ Wq, const float* __restrict__ bq,
    const float* __restrict__ Wk, const float* __restrict__ bk,
    const float* __restrict__ Wv, const float* __restrict__ bv,
    const float* __restrict__ Wg, const float* __restrict__ bg,
    float* __restrict__ qo, float* __restrict__ ko, float* __restrict__ vo, float* __restrict__ go)
{
    __shared__ float xn[4 * 576];
    const int tid = threadIdx.x;
    const int wid = tid >> 6, lane = tid & 63;
    const int row0 = blockIdx.x * 4;     // global row = b*512 + l ; never straddles b

    {   // each wave LNs one row (576 = 64*9)
        const float* xr = x + (size_t)(row0 + wid) * CDIM;
        float vals[9]; float s = 0.f, sq = 0.f;
#pragma unroll
        for (int u = 0; u < 9; ++u) {
            float v = xr[lane + 64 * u];
            vals[u] = v; s += v; sq += v * v;
        }
#pragma unroll
        for (int o = 32; o; o >>= 1) { s += __shfl_xor(s, o); sq += __shfl_xor(sq, o); }
        float m = s * (1.f / 576.f);
        float inv = rsqrtf(sq * (1.f / 576.f) - m * m + 1e-6f);
#pragma unroll
        for (int u = 0; u < 9; ++u) {
            int idx = lane + 64 * u;
            xn[wid * 576 + idx] = (vals[u] - m) * inv * ln1w[idx] + ln1b[idx];
        }
    }
    __syncthreads();

    // 2304 projection columns (4 mats x 3 grp x 192), 9 per thread, 4 rows each
    const float* Wt[9]; float bias[9]; int grpo[9]; float* outp[9];
    const int b = row0 >> 9, l = row0 & 511;
#pragma unroll
    for (int rr = 0; rr < 9; ++rr) {
        int o = tid + 256 * rr;
        int mi = o / 576, t = o % 576;
        int grp = t / 192, jj = t % 192;
        const float* W  = mi == 0 ? Wq : mi == 1 ? Wk : mi == 2 ? Wv : Wg;
        const float* bb = mi == 0 ? bq : mi == 1 ? bk : mi == 2 ? bv : bg;
        float* op       = mi == 0 ? qo : mi == 1 ? ko : mi == 2 ? vo : go;
        Wt[rr] = W + jj;
        bias[rr] = bb[jj];
        grpo[rr] = grp * 192;
        int h = jj / 24, d24 = jj % 24;
        outp[rr] = op + ((((size_t)b * 3 + grp) * HDIM + h) * LDIM + l) * DK3 + d24;
    }
    float acc[9][4] = {};
    for (int d = 0; d < 192; ++d) {
#pragma unroll
        for (int rr = 0; rr < 9; ++rr) {
            float w = Wt[rr][(size_t)d * 192];
#pragma unroll
            for (int r = 0; r < 4; ++r)
                acc[rr][r] += xn[r * 576 + grpo[rr] + d] * w;
        }
    }
#pragma unroll
    for (int rr = 0; rr < 9; ++rr)
#pragma unroll
        for (int r = 0; r < 4; ++r)
            outp[rr][(size_t)r * DK3] = acc[rr][r] + bias[rr];
}

// ---------------------------------------------------------------------------
// K2: pairBias = LN(pairX) @ Wp + bp -> bias[B,H,L,L]. wave per (b,i,j) row.
// grid=8192, 64 rows/block.
// Reduction: stage 1 (xor 8,16,32) -> lane l holds A_{l&7}[h] (class partial).
// Select h = lane>>3, butterfly over class bits (xor 1,2,4) -> full sum for
// head lane>>3; lanes with (lane&7)==0 write. (Round-1 bug: selecting h=lane&7
// produced the diagonal sum, identical for all heads.)
// ---------------------------------------------------------------------------
__global__ __launch_bounds__(256) void k_pairbias(
    const float* __restrict__ pairX, const float* __restrict__ ln2w, const float* __restrict__ ln2b,
    const float* __restrict__ Wp, const float* __restrict__ bp,
    float* __restrict__ bias)
{
    __shared__ float WpT[8 * 128];     // transposed: WpT[h*128+d]
    __shared__ float lw[128], lb[128];
    const int tid = threadIdx.x;
    if (tid < 128) { lw[tid] = ln2w[tid]; lb[tid] = ln2b[tid]; }
    for (int i = tid; i < 1024; i += 256) WpT[(i & 7) * 128 + (i >> 3)] = Wp[i];
    __syncthreads();

    const int wid = tid >> 6, lane = tid & 63;
    const int d0 = lane * 2;
    const float w0 = lw[d0], w1 = lw[d0 + 1], b0 = lb[d0], b1 = lb[d0 + 1];
    float wp0[8], wp1[8];
#pragma unroll
    for (int h = 0; h < 8; ++h) { wp0[h] = WpT[h * 128 + d0]; wp1[h] = WpT[h * 128 + d0 + 1]; }
    const int hsel = lane >> 3;
    const float bpv = bp[hsel];

    for (int it = 0; it < 16; ++it) {
        size_t row = (size_t)blockIdx.x * 64 + it * 4 + wid;   // b*L*L + i*L + j
        const float2 v = *(const float2*)(pairX + row * CPD + d0);
        float s = v.x + v.y, sq = v.x * v.x + v.y * v.y;
#pragma unroll
        for (int o = 32; o; o >>= 1) { s += __shfl_xor(s, o); sq += __shfl_xor(sq, o); }
        float m = s * (1.f / 128.f);
        float inv = rsqrtf(sq * (1.f / 128.f) - m * m + 1e-6f);
        float p0 = (v.x - m) * inv * w0 + b0;
        float p1 = (v.y - m) * inv * w1 + b1;
        float a[8];
#pragma unroll
        for (int h = 0; h < 8; ++h) a[h] = p0 * wp0[h] + p1 * wp1[h];
        // stage 1: reduce over lane bits 3,4,5 -> per-class partials A_{lane&7}[h]
#pragma unroll
        for (int h = 0; h < 8; ++h) {
            a[h] += __shfl_xor(a[h], 8);
            a[h] += __shfl_xor(a[h], 16);
            a[h] += __shfl_xor(a[h], 32);
        }
        // stage 2: lane picks h = lane>>3, reduce across classes (bits 0,1,2)
        float vsel = hsel == 0 ? a[0] : hsel == 1 ? a[1] : hsel == 2 ? a[2] : hsel == 3 ? a[3]
                   : hsel == 4 ? a[4] : hsel == 5 ? a[5] : hsel == 6 ? a[6] : a[7];
        vsel += __shfl_xor(vsel, 1);
        vsel += __shfl_xor(vsel, 2);
        vsel += __shfl_xor(vsel, 4);
        if ((lane & 7) == 0) {
            size_t bb = row >> 18;
            size_t i = (row >> 9) & 511, j = row & 511;
            bias[((bb * HDIM + hsel) * LDIM + i) * LDIM + j] = vsel + bpv;
        }
    }
}

// ---------------------------------------------------------------------------
// K3: oriQK = q.k^T (K=24) + bias.  block = (bch, itile of 64 rows). grid=384.
// ---------------------------------------------------------------------------
__global__ __launch_bounds__(256) void k_qkmat(
    const float* __restrict__ q, const float* __restrict__ k,
    const float* __restrict__ bias, float* __restrict__ oriQK)
{
    __shared__ float Kl[512 * 25];   // pad 24->25 (stride-24 = 16-way bank alias)
    __shared__ float Ql[64 * 25];
    const int tid = threadIdx.x;
    const int bch = blockIdx.x >> 3;       // b*24 + c*8 + h
    const int itile = blockIdx.x & 7;
    const float* kp = k + (size_t)bch * 512 * 24;
    const float* qp = q + (size_t)bch * 512 * 24 + (size_t)itile * 64 * 24;
    for (int idx = tid; idx < 512 * 24; idx += 256) {
        int j = idx / 24, d = idx - j * 24;
        Kl[j * 25 + d] = kp[idx];
    }
    for (int idx = tid; idx < 64 * 24; idx += 256) {
        int i = idx / 24, d = idx - i * 24;
        Ql[i * 25 + d] = qp[idx];
    }
    __syncthreads();

    const int ti = tid >> 4, tj = tid & 15;
    const int b = bch / 24, h = bch & 7;
    const float* biasp = bias + ((size_t)(b * 8 + h) * 512 + itile * 64) * 512;
    float* outp = oriQK + (size_t)bch * 262144 + (size_t)itile * 64 * 512;

    for (int cc = 0; cc < 4; ++cc) {
        float acc[4][8] = {};
        for (int d = 0; d < 24; ++d) {
            float qv[4], kv[8];
#pragma unroll
            for (int r = 0; r < 4; ++r) qv[r] = Ql[(ti * 4 + r) * 25 + d];
#pragma unroll
            for (int u = 0; u < 8; ++u) kv[u] = Kl[(cc * 128 + u * 16 + tj) * 25 + d];
#pragma unroll
            for (int r = 0; r < 4; ++r)
#pragma unroll
                for (int u = 0; u < 8; ++u) acc[r][u] += qv[r] * kv[u];
        }
#pragma unroll
        for (int r = 0; r < 4; ++r) {
            int i = ti * 4 + r;
#pragma unroll
            for (int u = 0; u < 8; ++u) {
                int j = cc * 128 + u * 16 + tj;
                outp[(size_t)i * 512 + j] = acc[r][u] + biasp[(size_t)i * 512 + j];
            }
        }
    }
}

// ---------------------------------------------------------------------------
// K4: 5x5 conv over (L,L), 24 in-ch (3 branches x 8h) -> 8h, summed over
// branches; fused epilogue writes qk = (ori+conv)/sqrt(72) and
// gq = gelu(mean_c qk) in [B,L,L,H].  32x32 tile + halo in LDS. grid=512.
// ---------------------------------------------------------------------------
__global__ __launch_bounds__(256) void k_conv(
    const float* __restrict__ oriQK, const float* __restrict__ convW, const float* __restrict__ convB,
    float* __restrict__ qk, float* __restrict__ gq)
{
    __shared__ float tile[24 * 36 * 40];   // row stride 40 -> 2-way-max bank phase for b128
    __shared__ float wS[4800];
    __shared__ float cbS[8];
    const int tid = threadIdx.x;
    const int bx = blockIdx.x;
    const int b = bx >> 8, rem = bx & 255;
    const int i0 = (rem >> 4) * 32, j0 = (rem & 15) * 32;

    for (int i = tid; i < 4800; i += 256) wS[i] = convW[i];
    if (tid < 8) cbS[tid] = convB[tid] + convB[8 + tid] + convB[16 + tid];
    for (int idx = tid; idx < 24 * 36 * 36; idx += 256) {
        int ch = idx / 1296, r = idx - ch * 1296;
        int ii = r / 36, jj = r - ii * 36;
        int gi = i0 - 2 + ii, gj = j0 - 2 + jj;
        float v = 0.f;
        if ((unsigned)gi < 512u && (unsigned)gj < 512u)
            v = oriQK[((size_t)(b * 24 + ch) << 18) + ((size_t)gi << 9) + gj];
        tile[ch * 1440 + ii * 40 + jj] = v;
    }
    __syncthreads();

    const int jg = tid & 7, ii = tid >> 3;   // 8 col-groups x 32 rows
    const int j4 = jg * 4;
    float acc[4][8] = {};                    // [jcol][h_out]
    for (int c = 0; c < 3; ++c)
        for (int hi = 0; hi < 8; ++hi) {
            const float* tch = &tile[(c * 8 + hi) * 1440];
            const float* wch = &wS[c * 1600 + hi * 25];   // + h*200 + kh*5 + kw
#pragma unroll
            for (int kh = 0; kh < 5; ++kh) {
                const float* trow = &tch[(ii + kh) * 40 + j4];
                float v[8];
                *(float4*)&v[0] = *(const float4*)&trow[0];
                *(float4*)&v[4] = *(const float4*)&trow[4];
#pragma unroll
                for (int kw = 0; kw < 5; ++kw) {
#pragma unroll
                    for (int h = 0; h < 8; ++h) {
                        float w = wch[h * 200 + kh * 5 + kw];
                        acc[0][h] += w * v[kw];
                        acc[1][h] += w * v[kw + 1];
                        acc[2][h] += w * v[kw + 2];
                        acc[3][h] += w * v[kw + 3];
                    }
                }
            }
        }

    const int gi = i0 + ii, gj = j0 + j4;
    float* qkb = qk + ((size_t)(b * 24) << 18) + ((size_t)gi << 9) + gj;
    float gqv[4][8];
#pragma unroll
    for (int h = 0; h < 8; ++h) {
        float cv = cbS[h];
        float c0 = acc[0][h] + cv, c1 = acc[1][h] + cv, c2 = acc[2][h] + cv, c3 = acc[3][h] + cv;
        float m0 = 0, m1 = 0, m2 = 0, m3 = 0;
#pragma unroll
        for (int c = 0; c < 3; ++c) {
            const float* tr = &tile[(c * 8 + h) * 1440 + (ii + 2) * 40 + j4 + 2];
            float t0 = tr[0], t1 = tr[1], t2 = tr[2], t3 = tr[3];
            m0 += t0; m1 += t1; m2 += t2; m3 += t3;
            float4 o = make_float4((t0 + c0) * INV_DIV, (t1 + c1) * INV_DIV,
                                   (t2 + c2) * INV_DIV, (t3 + c3) * INV_DIV);
            *(float4*)(qkb + ((size_t)(c * 8 + h) << 18)) = o;
        }
        gqv[0][h] = gelu_exact((m0 * (1.f / 3.f) + c0) * INV_DIV);
        gqv[1][h] = gelu_exact((m1 * (1.f / 3.f) + c1) * INV_DIV);
        gqv[2][h] = gelu_exact((m2 * (1.f / 3.f) + c2) * INV_DIV);
        gqv[3][h] = gelu_exact((m3 * (1.f / 3.f) + c3) * INV_DIV);
    }
    float* gqb = gq + (((size_t)(b * 512 + gi) << 9) + gj) * 8;
#pragma unroll
    for (int jc = 0; jc < 4; ++jc) {
        *(float4*)(gqb + jc * 8)     = make_float4(gqv[jc][0], gqv[jc][1], gqv[jc][2], gqv[jc][3]);
        *(float4*)(gqb + jc * 8 + 4) = make_float4(gqv[jc][4], gqv[jc][5], gqv[jc][6], gqv[jc][7]);
    }
}

// ---------------------------------------------------------------------------
// K5: out2 = gq(8) @ Wpr(8x128) + bpr.  grid=2048, 256 pos/block.
// ---------------------------------------------------------------------------
__global__ __launch_bounds__(256) void k_out2(
    const float* __restrict__ gq, const float* __restrict__ Wpr, const float* __restrict__ bpr,
    float* __restrict__ out2)
{
    __shared__ float WprS[8 * 128];
    __shared__ float bprS[128];
    const int tid = threadIdx.x;
    for (int i = tid; i < 1024; i += 256) WprS[i] = Wpr[i];
    if (tid < 128) bprS[tid] = bpr[tid];
    __syncthreads();

    const int p = (tid & 31) * 4;
    float4 wv[8];
#pragma unroll
    for (int h = 0; h < 8; ++h) wv[h] = *(const float4*)&WprS[h * 128 + p];
    const float4 bv = *(const float4*)&bprS[p];

    size_t pos0 = (size_t)blockIdx.x * 256 + (tid >> 5);
    for (int it = 0; it < 32; ++it) {
        size_t pos = pos0 + it * 8;
        const float4 ga = *(const float4*)(gq + pos * 8);
        const float4 gb = *(const float4*)(gq + pos * 8 + 4);
        float4 o = bv;
        o.x += ga.x * wv[0].x + ga.y * wv[1].x + ga.z * wv[2].x + ga.w * wv[3].x
             + gb.x * wv[4].x + gb.y * wv[5].x + gb.z * wv[6].x + gb.w * wv[7].x;
        o.y += ga.x * wv[0].y + ga.y * wv[1].y + ga.z * wv[2].y + ga.w * wv[3].y
             + gb.x * wv[4].y + gb.y * wv[5].y + gb.z * wv[6].y + gb.w * wv[7].y;
        o.z += ga.x * wv[0].z + ga.y * wv[1].z + ga.z * wv[2].z + ga.w * wv[3].z
             + gb.x * wv[4].z + gb.y * wv[5].z + gb.z * wv[6].z + gb.w * wv[7].z;
        o.w += ga.x * wv[0].w + ga.y * wv[1].w + ga.z * wv[2].w + ga.w * wv[3].w
             + gb.x * wv[4].w + gb.y * wv[5].w + gb.z * wv[6].w + gb.w * wv[7].w;
        *(float4*)(out2 + pos * 128 + p) = o;
    }
}

// ---------------------------------------------------------------------------
// K6: softmax over qk rows + P@V + sigmoid(gate).  wave per row, V in LDS.
// grid=768 (48 bch x 16 itiles of 32 rows).
// ---------------------------------------------------------------------------
__global__ __launch_bounds__(256) void k_softmax_pv(
    const float* __restrict__ qk, const float* __restrict__ v, const float* __restrict__ gate,
    float* __restrict__ houts)
{
    __shared__ float Vl[512 * 25];   // pad 24->25
    const int tid = threadIdx.x;
    const int bch = blockIdx.x >> 4, itile = blockIdx.x & 15;
    const float* vp = v + (size_t)bch * (512 * 24);
    for (int idx = tid; idx < 512 * 24; idx += 256) {
        int j = idx / 24, d = idx - j * 24;
        Vl[j * 25 + d] = vp[idx];
    }
    __syncthreads();

    const int wid = tid >> 6, lane = tid & 63;
    const int b = bch / 24, c = (bch % 24) >> 3, h = bch & 7;
    for (int rr = 0; rr < 8; ++rr) {
        const int i = itile * 32 + wid * 8 + rr;
        const float* row = qk + ((size_t)bch * 512 + i) * 512;
        float e[8]; float mx = -1e30f;
#pragma unroll
        for (int u = 0; u < 8; ++u) { e[u] = row[lane + 64 * u]; mx = fmaxf(mx, e[u]); }
#pragma unroll
        for (int o = 32; o; o >>= 1) mx = fmaxf(mx, __shfl_xor(mx, o));
        float s = 0.f;
#pragma unroll
        for (int u = 0; u < 8; ++u) { e[u] = __expf(e[u] - mx); s += e[u]; }
#pragma unroll
        for (int o = 32; o; o >>= 1) s += __shfl_xor(s, o);
        float inv = 1.f / s;
        float acc[24] = {};
#pragma unroll
        for (int u = 0; u < 8; ++u) {
            float p = e[u] * inv;
            const float* vr = &Vl[(u * 64 + lane) * 25];
#pragma unroll
            for (int d = 0; d < 24; ++d) acc[d] += p * vr[d];
        }
#pragma unroll
        for (int o = 32; o; o >>= 1)
#pragma unroll
            for (int d = 0; d < 24; ++d) acc[d] += __shfl_down(acc[d], o);
        if (lane == 0) {
            const float* gp = gate + ((size_t)bch * 512 + i) * 24;
            float* op = houts + ((size_t)(b * 512 + i)) * 576 + c * 192 + h * 24;
#pragma unroll
            for (int d = 0; d < 24; ++d) {
                float gv = gp[d];
                op[d] = acc[d] / (1.f + __expf(-gv));
            }
        }
    }
}

// ---------------------------------------------------------------------------
// K7: out1 = houts @ Wo + bo + x*g.  4 rows/block, grid=256.
// ---------------------------------------------------------------------------
__global__ __launch_bounds__(256) void k_out1(
    const float* __restrict__ houts, const float* __restrict__ Wo, const float* __restrict__ bo,
    const float* __restrict__ x, const float* __restrict__ gsc,
    float* __restrict__ out1)
{
    __shared__ float hS[4 * 576];
    const int tid = threadIdx.x;
    const int l0 = blockIdx.x * 4;
    for (int idx = tid; idx < 4 * 576; idx += 256)
        hS[idx] = houts[(size_t)l0 * 576 + idx];
    __syncthreads();

    float acc0[4] = {}, acc1[4] = {}, acc2[4] = {};
    const bool has3 = (tid < 64);
    for (int d = 0; d < 576; ++d) {
        float h0 = hS[d], h1 = hS[576 + d], h2 = hS[1152 + d], h3 = hS[1728 + d];
        const float* wr = Wo + (size_t)d * 576;
        float w0 = wr[tid], w1 = wr[tid + 256];
        acc0[0] += h0 * w0; acc0[1] += h1 * w0; acc0[2] += h2 * w0; acc0[3] += h3 * w0;
        acc1[0] += h0 * w1; acc1[1] += h1 * w1; acc1[2] += h2 * w1; acc1[3] += h3 * w1;
        if (has3) {
            float w2 = wr[tid + 512];
            acc2[0] += h0 * w2; acc2[1] += h1 * w2; acc2[2] += h2 * w2; acc2[3] += h3 * w2;
        }
    }
    const float gv = gsc[0];
    {
        int j = tid; float bj = bo[j];
#pragma unroll
        for (int r = 0; r < 4; ++r) {
            size_t idx = (size_t)(l0 + r) * 576 + j;
            out1[idx] = acc0[r] + bj + x[idx] * gv;
        }
    }
    {
        int j = tid + 256; float bj = bo[j];
#pragma unroll
        for (int r = 0; r < 4; ++r) {
            size_t idx = (size_t)(l0 + r) * 576 + j;
            out1[idx] = acc1[r] + bj + x[idx] * gv;
        }
    }
    if (has3) {
        int j = tid + 512; float bj = bo[j];
#pragma unroll
        for (int r = 0; r < 4; ++r) {
            size_t idx = (size_t)(l0 + r) * 576 + j;
            out1[idx] = acc2[r] + bj + x[idx] * gv;
        }
    }
}

// ---------------------------------------------------------------------------
extern "C" void kernel_launch(void* const* d_in, const int* in_sizes, int n_in,
                              void* d_out, int out_size, void* d_ws, size_t ws_size,
                              hipStream_t stream) {
    const float* x     = (const float*)d_in[0];
    const float* pairX = (const float*)d_in[1];
    const float* g     = (const float*)d_in[2];
    const float* ln1w  = (const float*)d_in[3];
    const float* ln1b  = (const float*)d_in[4];
    const float* ln2w  = (const float*)d_in[5];
    const float* ln2b  = (const float*)d_in[6];
    const float* Wq    = (const float*)d_in[7];
    const float* bq    = (const float*)d_in[8];
    const float* Wk    = (const float*)d_in[9];
    const float* bk    = (const float*)d_in[10];
    const float* Wv    = (const float*)d_in[11];
    const float* bv    = (const float*)d_in[12];
    const float* Wg    = (const float*)d_in[13];
    const float* bg    = (const float*)d_in[14];
    const float* convW = (const float*)d_in[15];
    const float* convB = (const float*)d_in[16];
    const float* Wp    = (const float*)d_in[17];
    const float* bp    = (const float*)d_in[18];
    const float* Wpr   = (const float*)d_in[19];
    const float* bpr   = (const float*)d_in[20];
    const float* Wo    = (const float*)d_in[21];
    const float* bo    = (const float*)d_in[22];

    float* ws   = (float*)d_ws;
    float* q    = ws + OFF_Q;
    float* k    = ws + OFF_K;
    float* vv   = ws + OFF_V;
    float* gt   = ws + OFF_G;
    float* bias = ws + OFF_BIAS;
    float* gq   = ws + OFF_BIAS;   // alias: bias dead after k_qkmat
    float* ori  = ws + OFF_ORI;
    float* qkb  = ws + OFF_QK;
    float* hout = ws + OFF_H;

    float* out1 = (float*)d_out;
    float* out2 = out1 + 589824;

    k_ln_proj<<<dim3(256), dim3(256), 0, stream>>>(x, ln1w, ln1b, Wq, bq, Wk, bk, Wv, bv, Wg, bg,
                                                   q, k, vv, gt);
    k_pairbias<<<dim3(8192), dim3(256), 0, stream>>>(pairX, ln2w, ln2b, Wp, bp, bias);
    k_qkmat<<<dim3(384), dim3(256), 0, stream>>>(q, k, bias, ori);
    k_conv<<<dim3(512), dim3(256), 0, stream>>>(ori, convW, convB, qkb, gq);
    k_out2<<<dim3(2048), dim3(256), 0, stream>>>(gq, Wpr, bpr, out2);
    k_softmax_pv<<<dim3(768), dim3(256), 0, stream>>>(qkb, vv, gt, hout);
    k_out1<<<dim3(256), dim3(256), 0, stream>>>(hout, Wo, bo, x, g, out1);
}

// Round 3
// 725.240 us; speedup vs baseline: 1.4669x; 1.4669x over previous
//
#include <hip/hip_runtime.h>
#include <hip/hip_bf16.h>

// Problem constants
#define BDIM 2
#define LDIM 512
#define CDIM 576
#define HDIM 8
#define CPD  128
#define DK3  24
#define INV_DIV 0.117851130197757920f   // 1/sqrt(72)

// Workspace layout (floats). Total = 32,899,072 floats = 125.5 MiB required in d_ws.
static constexpr size_t OFF_Q    = 0;                       // [B,3,H,L,24] 589824
static constexpr size_t OFF_K    = 589824;
static constexpr size_t OFF_V    = 1179648;
static constexpr size_t OFF_G    = 1769472;
static constexpr size_t OFF_BIAS = 2359296;                 // [B,H,L,L] 4194304 ; reused as gq [B,L,L,H] after k_qkmat
static constexpr size_t OFF_ORI  = OFF_BIAS + 4194304;      // [B,3,H,L,L] 12582912
static constexpr size_t OFF_QK   = OFF_ORI + 12582912;      // [B,3,H,L,L] 12582912
static constexpr size_t OFF_H    = OFF_QK + 12582912;       // [B*L,576]   589824

__device__ __forceinline__ float gelu_exact(float v) {
    return 0.5f * v * (1.f + erff(v * 0.70710678118654752f));
}

// ---------------------------------------------------------------------------
// K1: LN(x) + one of q/k/v/gate projection per block.  grid=1024
// (256 row-groups x 4 matrices).  Per block: LN 4 rows (redundant 4x, cheap),
// then 576 cols x 4 rows of ONE projection.
// ---------------------------------------------------------------------------
__global__ __launch_bounds__(256) void k_ln_proj(
    const float* __restrict__ x, const float* __restrict__ ln1w, const float* __restrict__ ln1b,
    const float* __restrict__ Wq, const float* __restrict__ bq,
    const float* __restrict__ Wk, const float* __restrict__ bk,
    const float* __restrict__ Wv, const float* __restrict__ bv,
    const float* __restrict__ Wg, const float* __restrict__ bg,
    float* __restrict__ qo, float* __restrict__ ko, float* __restrict__ vo, float* __restrict__ go)
{
    __shared__ float xn[4 * 576];
    const int tid = threadIdx.x;
    const int wid = tid >> 6, lane = tid & 63;
    const int mi = blockIdx.x & 3;
    const int row0 = (blockIdx.x >> 2) * 4;   // b*512 + l ; never straddles b

    {   // each wave LNs one row (576 = 64*9)
        const float* xr = x + (size_t)(row0 + wid) * CDIM;
        float vals[9]; float s = 0.f, sq = 0.f;
#pragma unroll
        for (int u = 0; u < 9; ++u) {
            float v = xr[lane + 64 * u];
            vals[u] = v; s += v; sq += v * v;
        }
#pragma unroll
        for (int o = 32; o; o >>= 1) { s += __shfl_xor(s, o); sq += __shfl_xor(sq, o); }
        float m = s * (1.f / 576.f);
        float inv = rsqrtf(sq * (1.f / 576.f) - m * m + 1e-6f);
#pragma unroll
        for (int u = 0; u < 9; ++u) {
            int idx = lane + 64 * u;
            xn[wid * 576 + idx] = (vals[u] - m) * inv * ln1w[idx] + ln1b[idx];
        }
    }
    __syncthreads();

    const float* W  = mi == 0 ? Wq : mi == 1 ? Wk : mi == 2 ? Wv : Wg;
    const float* bb = mi == 0 ? bq : mi == 1 ? bk : mi == 2 ? bv : bg;
    float* op       = mi == 0 ? qo : mi == 1 ? ko : mi == 2 ? vo : go;
    const int b = row0 >> 9, l = row0 & 511;

    // cols j0=tid, j1=tid+256, j2=tid+512 (tid<64 only)
    const int j0 = tid, j1 = tid + 256;
    const int g0 = j0 / 192, g1 = j1 / 192;          // g2 = 2
    const int q0 = j0 - 192 * g0, q1 = j1 - 192 * g1, q2 = tid + 128;
    const bool has2 = (tid < 64);
    float acc0[4] = {}, acc1[4] = {}, acc2[4] = {};
    for (int d = 0; d < 192; ++d) {
        float w0 = W[(size_t)d * 192 + q0];
        float w1 = W[(size_t)d * 192 + q1];
        float x0 = xn[g0 * 192 + d],            x0b = xn[576 + g0 * 192 + d];
        float x0c = xn[1152 + g0 * 192 + d],    x0d = xn[1728 + g0 * 192 + d];
        float x1 = xn[g1 * 192 + d],            x1b = xn[576 + g1 * 192 + d];
        float x1c = xn[1152 + g1 * 192 + d],    x1d = xn[1728 + g1 * 192 + d];
        acc0[0] += x0 * w0; acc0[1] += x0b * w0; acc0[2] += x0c * w0; acc0[3] += x0d * w0;
        acc1[0] += x1 * w1; acc1[1] += x1b * w1; acc1[2] += x1c * w1; acc1[3] += x1d * w1;
        if (has2) {
            float w2 = W[(size_t)d * 192 + q2];
            float x2 = xn[384 + d], x2b = xn[576 + 384 + d];
            float x2c = xn[1152 + 384 + d], x2d = xn[1728 + 384 + d];
            acc2[0] += x2 * w2; acc2[1] += x2b * w2; acc2[2] += x2c * w2; acc2[3] += x2d * w2;
        }
    }
    // store: out[((b*3+grp)*8+h)*512*24 + (l+r)*24 + d24]
    {
        int h = q0 / 24, d24 = q0 % 24;
        float bj = bb[q0];
        float* o = op + ((((size_t)b * 3 + g0) * HDIM + h) * LDIM + l) * DK3 + d24;
#pragma unroll
        for (int r = 0; r < 4; ++r) o[r * DK3] = acc0[r] + bj;
    }
    {
        int h = q1 / 24, d24 = q1 % 24;
        float bj = bb[q1];
        float* o = op + ((((size_t)b * 3 + g1) * HDIM + h) * LDIM + l) * DK3 + d24;
#pragma unroll
        for (int r = 0; r < 4; ++r) o[r * DK3] = acc1[r] + bj;
    }
    if (has2) {
        int h = q2 / 24, d24 = q2 % 24;
        float bj = bb[q2];
        float* o = op + ((((size_t)b * 3 + 2) * HDIM + h) * LDIM + l) * DK3 + d24;
#pragma unroll
        for (int r = 0; r < 4; ++r) o[r * DK3] = acc2[r] + bj;
    }
}

// ---------------------------------------------------------------------------
// K2: pairBias = LN(pairX) @ Wp + bp -> bias[B,H,L,L]. wave per (b,i,j) row.
// grid=8192, 64 rows/block.
// ---------------------------------------------------------------------------
__global__ __launch_bounds__(256) void k_pairbias(
    const float* __restrict__ pairX, const float* __restrict__ ln2w, const float* __restrict__ ln2b,
    const float* __restrict__ Wp, const float* __restrict__ bp,
    float* __restrict__ bias)
{
    __shared__ float WpT[8 * 128];     // transposed: WpT[h*128+d]
    __shared__ float lw[128], lb[128];
    const int tid = threadIdx.x;
    if (tid < 128) { lw[tid] = ln2w[tid]; lb[tid] = ln2b[tid]; }
    for (int i = tid; i < 1024; i += 256) WpT[(i & 7) * 128 + (i >> 3)] = Wp[i];
    __syncthreads();

    const int wid = tid >> 6, lane = tid & 63;
    const int d0 = lane * 2;
    const float w0 = lw[d0], w1 = lw[d0 + 1], b0 = lb[d0], b1 = lb[d0 + 1];
    float wp0[8], wp1[8];
#pragma unroll
    for (int h = 0; h < 8; ++h) { wp0[h] = WpT[h * 128 + d0]; wp1[h] = WpT[h * 128 + d0 + 1]; }
    const int hsel = lane >> 3;
    const float bpv = bp[hsel];

    for (int it = 0; it < 16; ++it) {
        size_t row = (size_t)blockIdx.x * 64 + it * 4 + wid;   // b*L*L + i*L + j
        const float2 v = *(const float2*)(pairX + row * CPD + d0);
        float s = v.x + v.y, sq = v.x * v.x + v.y * v.y;
#pragma unroll
        for (int o = 32; o; o >>= 1) { s += __shfl_xor(s, o); sq += __shfl_xor(sq, o); }
        float m = s * (1.f / 128.f);
        float inv = rsqrtf(sq * (1.f / 128.f) - m * m + 1e-6f);
        float p0 = (v.x - m) * inv * w0 + b0;
        float p1 = (v.y - m) * inv * w1 + b1;
        float a[8];
#pragma unroll
        for (int h = 0; h < 8; ++h) a[h] = p0 * wp0[h] + p1 * wp1[h];
#pragma unroll
        for (int h = 0; h < 8; ++h) {
            a[h] += __shfl_xor(a[h], 8);
            a[h] += __shfl_xor(a[h], 16);
            a[h] += __shfl_xor(a[h], 32);
        }
        float vsel = hsel == 0 ? a[0] : hsel == 1 ? a[1] : hsel == 2 ? a[2] : hsel == 3 ? a[3]
                   : hsel == 4 ? a[4] : hsel == 5 ? a[5] : hsel == 6 ? a[6] : a[7];
        vsel += __shfl_xor(vsel, 1);
        vsel += __shfl_xor(vsel, 2);
        vsel += __shfl_xor(vsel, 4);
        if ((lane & 7) == 0) {
            size_t bb = row >> 18;
            size_t i = (row >> 9) & 511, j = row & 511;
            bias[((bb * HDIM + hsel) * LDIM + i) * LDIM + j] = vsel + bpv;
        }
    }
}

// ---------------------------------------------------------------------------
// K3: oriQK = q.k^T (K=24) + bias.  block = (bch, itile of 32 rows). grid=768.
// ---------------------------------------------------------------------------
__global__ __launch_bounds__(256) void k_qkmat(
    const float* __restrict__ q, const float* __restrict__ k,
    const float* __restrict__ bias, float* __restrict__ oriQK)
{
    __shared__ float Kl[512 * 25];   // pad 24->25
    __shared__ float Ql[32 * 25];
    const int tid = threadIdx.x;
    const int bch = blockIdx.x >> 4;       // b*24 + c*8 + h
    const int itile = blockIdx.x & 15;
    const float* kp = k + (size_t)bch * 512 * 24;
    const float* qp = q + (size_t)bch * 512 * 24 + (size_t)itile * 32 * 24;
    for (int idx = tid; idx < 512 * 24; idx += 256) {
        int j = idx / 24, d = idx - j * 24;
        Kl[j * 25 + d] = kp[idx];
    }
    for (int idx = tid; idx < 32 * 24; idx += 256) {
        int i = idx / 24, d = idx - i * 24;
        Ql[i * 25 + d] = qp[idx];
    }
    __syncthreads();

    const int ti = tid >> 4, tj = tid & 15;   // ti 0..15 -> 2 rows each
    const int b = bch / 24, h = bch & 7;
    const float* biasp = bias + ((size_t)(b * 8 + h) * 512 + itile * 32) * 512;
    float* outp = oriQK + (size_t)bch * 262144 + (size_t)itile * 32 * 512;

    for (int cc = 0; cc < 4; ++cc) {
        float acc[2][8] = {};
        for (int d = 0; d < 24; ++d) {
            float qv[2], kv[8];
#pragma unroll
            for (int r = 0; r < 2; ++r) qv[r] = Ql[(ti * 2 + r) * 25 + d];
#pragma unroll
            for (int u = 0; u < 8; ++u) kv[u] = Kl[(cc * 128 + u * 16 + tj) * 25 + d];
#pragma unroll
            for (int r = 0; r < 2; ++r)
#pragma unroll
                for (int u = 0; u < 8; ++u) acc[r][u] += qv[r] * kv[u];
        }
#pragma unroll
        for (int r = 0; r < 2; ++r) {
            int i = ti * 2 + r;
#pragma unroll
            for (int u = 0; u < 8; ++u) {
                int j = cc * 128 + u * 16 + tj;
                outp[(size_t)i * 512 + j] = acc[r][u] + biasp[(size_t)i * 512 + j];
            }
        }
    }
}

// ---------------------------------------------------------------------------
// K4: 5x5 conv over (L,L), 24 in-ch (3 branches x 8h) -> 8h, summed over
// branches; fused epilogue writes qk = (ori+conv)/sqrt(72) and
// gq = gelu(mean_c qk) in [B,L,L,H].  32x32 tile + halo in LDS. grid=512.
// ---------------------------------------------------------------------------
__global__ __launch_bounds__(256) void k_conv(
    const float* __restrict__ oriQK, const float* __restrict__ convW, const float* __restrict__ convB,
    float* __restrict__ qk, float* __restrict__ gq)
{
    __shared__ float tile[24 * 36 * 40];
    __shared__ float wS[4800];
    __shared__ float cbS[8];
    const int tid = threadIdx.x;
    const int bx = blockIdx.x;
    const int b = bx >> 8, rem = bx & 255;
    const int i0 = (rem >> 4) * 32, j0 = (rem & 15) * 32;

    for (int i = tid; i < 4800; i += 256) wS[i] = convW[i];
    if (tid < 8) cbS[tid] = convB[tid] + convB[8 + tid] + convB[16 + tid];
    for (int idx = tid; idx < 24 * 36 * 36; idx += 256) {
        int ch = idx / 1296, r = idx - ch * 1296;
        int ii = r / 36, jj = r - ii * 36;
        int gi = i0 - 2 + ii, gj = j0 - 2 + jj;
        float v = 0.f;
        if ((unsigned)gi < 512u && (unsigned)gj < 512u)
            v = oriQK[((size_t)(b * 24 + ch) << 18) + ((size_t)gi << 9) + gj];
        tile[ch * 1440 + ii * 40 + jj] = v;
    }
    __syncthreads();

    const int jg = tid & 7, ii = tid >> 3;
    const int j4 = jg * 4;
    float acc[4][8] = {};
    for (int c = 0; c < 3; ++c)
        for (int hi = 0; hi < 8; ++hi) {
            const float* tch = &tile[(c * 8 + hi) * 1440];
            const float* wch = &wS[c * 1600 + hi * 25];
#pragma unroll
            for (int kh = 0; kh < 5; ++kh) {
                const float* trow = &tch[(ii + kh) * 40 + j4];
                float v[8];
                *(float4*)&v[0] = *(const float4*)&trow[0];
                *(float4*)&v[4] = *(const float4*)&trow[4];
#pragma unroll
                for (int kw = 0; kw < 5; ++kw) {
#pragma unroll
                    for (int h = 0; h < 8; ++h) {
                        float w = wch[h * 200 + kh * 5 + kw];
                        acc[0][h] += w * v[kw];
                        acc[1][h] += w * v[kw + 1];
                        acc[2][h] += w * v[kw + 2];
                        acc[3][h] += w * v[kw + 3];
                    }
                }
            }
        }

    const int gi = i0 + ii, gj = j0 + j4;
    float* qkb = qk + ((size_t)(b * 24) << 18) + ((size_t)gi << 9) + gj;
    float gqv[4][8];
#pragma unroll
    for (int h = 0; h < 8; ++h) {
        float cv = cbS[h];
        float c0 = acc[0][h] + cv, c1 = acc[1][h] + cv, c2 = acc[2][h] + cv, c3 = acc[3][h] + cv;
        float m0 = 0, m1 = 0, m2 = 0, m3 = 0;
#pragma unroll
        for (int c = 0; c < 3; ++c) {
            const float* tr = &tile[(c * 8 + h) * 1440 + (ii + 2) * 40 + j4 + 2];
            float t0 = tr[0], t1 = tr[1], t2 = tr[2], t3 = tr[3];
            m0 += t0; m1 += t1; m2 += t2; m3 += t3;
            float4 o = make_float4((t0 + c0) * INV_DIV, (t1 + c1) * INV_DIV,
                                   (t2 + c2) * INV_DIV, (t3 + c3) * INV_DIV);
            *(float4*)(qkb + ((size_t)(c * 8 + h) << 18)) = o;
        }
        gqv[0][h] = gelu_exact((m0 * (1.f / 3.f) + c0) * INV_DIV);
        gqv[1][h] = gelu_exact((m1 * (1.f / 3.f) + c1) * INV_DIV);
        gqv[2][h] = gelu_exact((m2 * (1.f / 3.f) + c2) * INV_DIV);
        gqv[3][h] = gelu_exact((m3 * (1.f / 3.f) + c3) * INV_DIV);
    }
    float* gqb = gq + (((size_t)(b * 512 + gi) << 9) + gj) * 8;
#pragma unroll
    for (int jc = 0; jc < 4; ++jc) {
        *(float4*)(gqb + jc * 8)     = make_float4(gqv[jc][0], gqv[jc][1], gqv[jc][2], gqv[jc][3]);
        *(float4*)(gqb + jc * 8 + 4) = make_float4(gqv[jc][4], gqv[jc][5], gqv[jc][6], gqv[jc][7]);
    }
}

// ---------------------------------------------------------------------------
// K5: out2 = gq(8) @ Wpr(8x128) + bpr.  grid=2048, 256 pos/block.
// ---------------------------------------------------------------------------
__global__ __launch_bounds__(256) void k_out2(
    const float* __restrict__ gq, const float* __restrict__ Wpr, const float* __restrict__ bpr,
    float* __restrict__ out2)
{
    __shared__ float WprS[8 * 128];
    __shared__ float bprS[128];
    const int tid = threadIdx.x;
    for (int i = tid; i < 1024; i += 256) WprS[i] = Wpr[i];
    if (tid < 128) bprS[tid] = bpr[tid];
    __syncthreads();

    const int p = (tid & 31) * 4;
    float4 wv[8];
#pragma unroll
    for (int h = 0; h < 8; ++h) wv[h] = *(const float4*)&WprS[h * 128 + p];
    const float4 bv = *(const float4*)&bprS[p];

    size_t pos0 = (size_t)blockIdx.x * 256 + (tid >> 5);
    for (int it = 0; it < 32; ++it) {
        size_t pos = pos0 + it * 8;
        const float4 ga = *(const float4*)(gq + pos * 8);
        const float4 gb = *(const float4*)(gq + pos * 8 + 4);
        float4 o = bv;
        o.x += ga.x * wv[0].x + ga.y * wv[1].x + ga.z * wv[2].x + ga.w * wv[3].x
             + gb.x * wv[4].x + gb.y * wv[5].x + gb.z * wv[6].x + gb.w * wv[7].x;
        o.y += ga.x * wv[0].y + ga.y * wv[1].y + ga.z * wv[2].y + ga.w * wv[3].y
             + gb.x * wv[4].y + gb.y * wv[5].y + gb.z * wv[6].y + gb.w * wv[7].y;
        o.z += ga.x * wv[0].z + ga.y * wv[1].z + ga.z * wv[2].z + ga.w * wv[3].z
             + gb.x * wv[4].z + gb.y * wv[5].z + gb.z * wv[6].z + gb.w * wv[7].z;
        o.w += ga.x * wv[0].w + ga.y * wv[1].w + ga.z * wv[2].w + ga.w * wv[3].w
             + gb.x * wv[4].w + gb.y * wv[5].w + gb.z * wv[6].w + gb.w * wv[7].w;
        *(float4*)(out2 + pos * 128 + p) = o;
    }
}

// ---------------------------------------------------------------------------
// K6: softmax over qk rows + P@V + sigmoid(gate).  wave per row, V in LDS.
// grid=768 (48 bch x 16 itiles of 32 rows).
// ---------------------------------------------------------------------------
__global__ __launch_bounds__(256) void k_softmax_pv(
    const float* __restrict__ qk, const float* __restrict__ v, const float* __restrict__ gate,
    float* __restrict__ houts)
{
    __shared__ float Vl[512 * 25];   // pad 24->25
    const int tid = threadIdx.x;
    const int bch = blockIdx.x >> 4, itile = blockIdx.x & 15;
    const float* vp = v + (size_t)bch * (512 * 24);
    for (int idx = tid; idx < 512 * 24; idx += 256) {
        int j = idx / 24, d = idx - j * 24;
        Vl[j * 25 + d] = vp[idx];
    }
    __syncthreads();

    const int wid = tid >> 6, lane = tid & 63;
    const int b = bch / 24, c = (bch % 24) >> 3, h = bch & 7;
    for (int rr = 0; rr < 8; ++rr) {
        const int i = itile * 32 + wid * 8 + rr;
        const float* row = qk + ((size_t)bch * 512 + i) * 512;
        float e[8]; float mx = -1e30f;
#pragma unroll
        for (int u = 0; u < 8; ++u) { e[u] = row[lane + 64 * u]; mx = fmaxf(mx, e[u]); }
#pragma unroll
        for (int o = 32; o; o >>= 1) mx = fmaxf(mx, __shfl_xor(mx, o));
        float s = 0.f;
#pragma unroll
        for (int u = 0; u < 8; ++u) { e[u] = __expf(e[u] - mx); s += e[u]; }
#pragma unroll
        for (int o = 32; o; o >>= 1) s += __shfl_xor(s, o);
        float inv = 1.f / s;
        float acc[24] = {};
#pragma unroll
        for (int u = 0; u < 8; ++u) {
            float p = e[u] * inv;
            const float* vr = &Vl[(u * 64 + lane) * 25];
#pragma unroll
            for (int d = 0; d < 24; ++d) acc[d] += p * vr[d];
        }
#pragma unroll
        for (int o = 32; o; o >>= 1)
#pragma unroll
            for (int d = 0; d < 24; ++d) acc[d] += __shfl_down(acc[d], o);
        if (lane == 0) {
            const float* gp = gate + ((size_t)bch * 512 + i) * 24;
            float* op = houts + ((size_t)(b * 512 + i)) * 576 + c * 192 + h * 24;
#pragma unroll
            for (int d = 0; d < 24; ++d) {
                float gv = gp[d];
                op[d] = acc[d] / (1.f + __expf(-gv));
            }
        }
    }
}

// ---------------------------------------------------------------------------
// K7: out1 = houts @ Wo + bo + x*g.  Tiled GEMM: 32x64 tile, BK=32, grid=288.
// ---------------------------------------------------------------------------
__global__ __launch_bounds__(256) void k_out1(
    const float* __restrict__ houts, const float* __restrict__ Wo, const float* __restrict__ bo,
    const float* __restrict__ x, const float* __restrict__ gsc,
    float* __restrict__ out1)
{
    __shared__ float As[32 * 33];   // [m][k], stride 33 (conflict-free writes)
    __shared__ float Bs[32 * 64];   // [k][n]
    const int tid = threadIdx.x;
    const int mt = blockIdx.x / 9, nt = blockIdx.x % 9;
    const int m0 = mt * 32, n0 = nt * 64;
    const int tn = tid & 15, tm = tid >> 4;      // tm,tn in 0..15
    float acc[2][4] = {};

    for (int kk = 0; kk < 576; kk += 32) {
        {
            int idx = tid;
#pragma unroll
            for (int i = 0; i < 4; ++i, idx += 256) {
                int k2 = idx & 31, m = idx >> 5;
                As[m * 33 + k2] = houts[(size_t)(m0 + m) * 576 + kk + k2];
            }
        }
        {
            int idx = tid;
#pragma unroll
            for (int i = 0; i < 8; ++i, idx += 256) {
                int n = idx & 63, k2 = idx >> 6;
                Bs[k2 * 64 + n] = Wo[(size_t)(kk + k2) * 576 + n0 + n];
            }
        }
        __syncthreads();
#pragma unroll
        for (int k2 = 0; k2 < 32; ++k2) {
            float a0 = As[(tm * 2 + 0) * 33 + k2];
            float a1 = As[(tm * 2 + 1) * 33 + k2];
            const float4 bv = *(const float4*)&Bs[k2 * 64 + tn * 4];
            acc[0][0] += a0 * bv.x; acc[0][1] += a0 * bv.y; acc[0][2] += a0 * bv.z; acc[0][3] += a0 * bv.w;
            acc[1][0] += a1 * bv.x; acc[1][1] += a1 * bv.y; acc[1][2] += a1 * bv.z; acc[1][3] += a1 * bv.w;
        }
        __syncthreads();
    }

    const float gv = gsc[0];
    const float4 b4 = *(const float4*)&bo[n0 + tn * 4];
#pragma unroll
    for (int r = 0; r < 2; ++r) {
        size_t row = (size_t)m0 + tm * 2 + r;
        size_t off = row * 576 + n0 + tn * 4;
        const float4 x4 = *(const float4*)&x[off];
        float4 o;
        o.x = acc[r][0] + b4.x + x4.x * gv;
        o.y = acc[r][1] + b4.y + x4.y * gv;
        o.z = acc[r][2] + b4.z + x4.z * gv;
        o.w = acc[r][3] + b4.w + x4.w * gv;
        *(float4*)&out1[off] = o;
    }
}

// ---------------------------------------------------------------------------
extern "C" void kernel_launch(void* const* d_in, const int* in_sizes, int n_in,
                              void* d_out, int out_size, void* d_ws, size_t ws_size,
                              hipStream_t stream) {
    const float* x     = (const float*)d_in[0];
    const float* pairX = (const float*)d_in[1];
    const float* g     = (const float*)d_in[2];
    const float* ln1w  = (const float*)d_in[3];
    const float* ln1b  = (const float*)d_in[4];
    const float* ln2w  = (const float*)d_in[5];
    const float* ln2b  = (const float*)d_in[6];
    const float* Wq    = (const float*)d_in[7];
    const float* bq    = (const float*)d_in[8];
    const float* Wk    = (const float*)d_in[9];
    const float* bk    = (const float*)d_in[10];
    const float* Wv    = (const float*)d_in[11];
    const float* bv    = (const float*)d_in[12];
    const float* Wg    = (const float*)d_in[13];
    const float* bg    = (const float*)d_in[14];
    const float* convW = (const float*)d_in[15];
    const float* convB = (const float*)d_in[16];
    const float* Wp    = (const float*)d_in[17];
    const float* bp    = (const float*)d_in[18];
    const float* Wpr   = (const float*)d_in[19];
    const float* bpr   = (const float*)d_in[20];
    const float* Wo    = (const float*)d_in[21];
    const float* bo    = (const float*)d_in[22];

    float* ws   = (float*)d_ws;
    float* q    = ws + OFF_Q;
    float* k    = ws + OFF_K;
    float* vv   = ws + OFF_V;
    float* gt   = ws + OFF_G;
    float* bias = ws + OFF_BIAS;
    float* gq   = ws + OFF_BIAS;   // alias: bias dead after k_qkmat
    float* ori  = ws + OFF_ORI;
    float* qkb  = ws + OFF_QK;
    float* hout = ws + OFF_H;

    float* out1 = (float*)d_out;
    float* out2 = out1 + 589824;

    k_ln_proj<<<dim3(1024), dim3(256), 0, stream>>>(x, ln1w, ln1b, Wq, bq, Wk, bk, Wv, bv, Wg, bg,
                                                    q, k, vv, gt);
    k_pairbias<<<dim3(8192), dim3(256), 0, stream>>>(pairX, ln2w, ln2b, Wp, bp, bias);
    k_qkmat<<<dim3(768), dim3(256), 0, stream>>>(q, k, bias, ori);
    k_conv<<<dim3(512), dim3(256), 0, stream>>>(ori, convW, convB, qkb, gq);
    k_out2<<<dim3(2048), dim3(256), 0, stream>>>(gq, Wpr, bpr, out2);
    k_softmax_pv<<<dim3(768), dim3(256), 0, stream>>>(qkb, vv, gt, hout);
    k_out1<<<dim3(288), dim3(256), 0, stream>>>(hout, Wo, bo, x, g, out1);
}

// Round 4
// 634.249 us; speedup vs baseline: 1.6774x; 1.1435x over previous
//
#include <hip/hip_runtime.h>
#include <hip/hip_bf16.h>

// Problem constants
#define BDIM 2
#define LDIM 512
#define CDIM 576
#define HDIM 8
#define CPD  128
#define DK3  24
#define INV_DIV 0.117851130197757920f   // 1/sqrt(72)

// Workspace layout (floats).
static constexpr size_t OFF_Q    = 0;                       // [B,3,H,L,24] 589824
static constexpr size_t OFF_K    = 589824;
static constexpr size_t OFF_V    = 1179648;
static constexpr size_t OFF_G    = 1769472;
static constexpr size_t OFF_BIAS = 2359296;                 // [B,H,L,L] 4194304 ; reused as gq [B,L,L,H] after k_qkmat
static constexpr size_t OFF_ORI  = OFF_BIAS + 4194304;      // [B,3,H,L,L] 12582912
static constexpr size_t OFF_QK   = OFF_ORI + 12582912;      // [B,3,H,L,L] 12582912
static constexpr size_t OFF_H    = OFF_QK + 12582912;       // [B*L,576]   589824
static constexpr size_t OFF_WPH  = OFF_H + 589824;          // [8][128] = 1024
static constexpr size_t OFF_CS   = OFF_WPH + 1024;          // [16]: colsum[8], cbp[8]

__device__ __forceinline__ float gelu_exact(float v) {
    return 0.5f * v * (1.f + erff(v * 0.70710678118654752f));
}

// ---------------------------------------------------------------------------
// K0: prep for pairbias.  wph[h][d] = ln2w[d]*Wp[d][h]; colsum/cbp folds.
// 1 block, 256 threads.
// ---------------------------------------------------------------------------
__global__ __launch_bounds__(256) void k_prep(
    const float* __restrict__ ln2w, const float* __restrict__ ln2b,
    const float* __restrict__ Wp, const float* __restrict__ bp,
    float* __restrict__ wph, float* __restrict__ csum)
{
    const int tid = threadIdx.x;
    for (int i = tid; i < 1024; i += 256) {
        int h = i >> 7, d = i & 127;
        wph[i] = ln2w[d] * Wp[d * 8 + h];
    }
    __syncthreads();
    if (tid < 16) {
        int h = tid & 7;
        float s = 0.f;
        if (tid < 8) {
            for (int d = 0; d < 128; ++d) s += wph[h * 128 + d];
            csum[h] = s;
        } else {
            for (int d = 0; d < 128; ++d) s += ln2b[d] * Wp[d * 8 + h];
            csum[8 + h] = s + bp[h];
        }
    }
}

// ---------------------------------------------------------------------------
// K1: LN(x) + one of q/k/v/gate projection per block.  grid=1024.
// ---------------------------------------------------------------------------
__global__ __launch_bounds__(256) void k_ln_proj(
    const float* __restrict__ x, const float* __restrict__ ln1w, const float* __restrict__ ln1b,
    const float* __restrict__ Wq, const float* __restrict__ bq,
    const float* __restrict__ Wk, const float* __restrict__ bk,
    const float* __restrict__ Wv, const float* __restrict__ bv,
    const float* __restrict__ Wg, const float* __restrict__ bg,
    float* __restrict__ qo, float* __restrict__ ko, float* __restrict__ vo, float* __restrict__ go)
{
    __shared__ float xn[4 * 576];
    const int tid = threadIdx.x;
    const int wid = tid >> 6, lane = tid & 63;
    const int mi = blockIdx.x & 3;
    const int row0 = (blockIdx.x >> 2) * 4;   // b*512 + l ; never straddles b

    {   // each wave LNs one row (576 = 64*9)
        const float* xr = x + (size_t)(row0 + wid) * CDIM;
        float vals[9]; float s = 0.f, sq = 0.f;
#pragma unroll
        for (int u = 0; u < 9; ++u) {
            float v = xr[lane + 64 * u];
            vals[u] = v; s += v; sq += v * v;
        }
#pragma unroll
        for (int o = 32; o; o >>= 1) { s += __shfl_xor(s, o); sq += __shfl_xor(sq, o); }
        float m = s * (1.f / 576.f);
        float inv = rsqrtf(sq * (1.f / 576.f) - m * m + 1e-6f);
#pragma unroll
        for (int u = 0; u < 9; ++u) {
            int idx = lane + 64 * u;
            xn[wid * 576 + idx] = (vals[u] - m) * inv * ln1w[idx] + ln1b[idx];
        }
    }
    __syncthreads();

    const float* W  = mi == 0 ? Wq : mi == 1 ? Wk : mi == 2 ? Wv : Wg;
    const float* bb = mi == 0 ? bq : mi == 1 ? bk : mi == 2 ? bv : bg;
    float* op       = mi == 0 ? qo : mi == 1 ? ko : mi == 2 ? vo : go;
    const int b = row0 >> 9, l = row0 & 511;

    const int j0 = tid, j1 = tid + 256;
    const int g0 = j0 / 192, g1 = j1 / 192;          // g2 = 2
    const int q0 = j0 - 192 * g0, q1 = j1 - 192 * g1, q2 = tid + 128;
    const bool has2 = (tid < 64);
    float acc0[4] = {}, acc1[4] = {}, acc2[4] = {};
    for (int d = 0; d < 192; ++d) {
        float w0 = W[(size_t)d * 192 + q0];
        float w1 = W[(size_t)d * 192 + q1];
        float x0 = xn[g0 * 192 + d],            x0b = xn[576 + g0 * 192 + d];
        float x0c = xn[1152 + g0 * 192 + d],    x0d = xn[1728 + g0 * 192 + d];
        float x1 = xn[g1 * 192 + d],            x1b = xn[576 + g1 * 192 + d];
        float x1c = xn[1152 + g1 * 192 + d],    x1d = xn[1728 + g1 * 192 + d];
        acc0[0] += x0 * w0; acc0[1] += x0b * w0; acc0[2] += x0c * w0; acc0[3] += x0d * w0;
        acc1[0] += x1 * w1; acc1[1] += x1b * w1; acc1[2] += x1c * w1; acc1[3] += x1d * w1;
        if (has2) {
            float w2 = W[(size_t)d * 192 + q2];
            float x2 = xn[384 + d], x2b = xn[576 + 384 + d];
            float x2c = xn[1152 + 384 + d], x2d = xn[1728 + 384 + d];
            acc2[0] += x2 * w2; acc2[1] += x2b * w2; acc2[2] += x2c * w2; acc2[3] += x2d * w2;
        }
    }
    {
        int h = q0 / 24, d24 = q0 % 24;
        float bj = bb[q0];
        float* o = op + ((((size_t)b * 3 + g0) * HDIM + h) * LDIM + l) * DK3 + d24;
#pragma unroll
        for (int r = 0; r < 4; ++r) o[r * DK3] = acc0[r] + bj;
    }
    {
        int h = q1 / 24, d24 = q1 % 24;
        float bj = bb[q1];
        float* o = op + ((((size_t)b * 3 + g1) * HDIM + h) * LDIM + l) * DK3 + d24;
#pragma unroll
        for (int r = 0; r < 4; ++r) o[r * DK3] = acc1[r] + bj;
    }
    if (has2) {
        int h = q2 / 24, d24 = q2 % 24;
        float bj = bb[q2];
        float* o = op + ((((size_t)b * 3 + 2) * HDIM + h) * LDIM + l) * DK3 + d24;
#pragma unroll
        for (int r = 0; r < 4; ++r) o[r * DK3] = acc2[r] + bj;
    }
}

// ---------------------------------------------------------------------------
// K2: pairBias.  ONE THREAD = ONE (b,i,j) ROW.  LN folded analytically:
// bias_h = inv*(dot_h - m*colsum_h) + cbp_h, dot_h = raw . wph[h].
// wph read with wave-uniform indices -> scalar loads; zero LDS, zero shfl.
// grid=2048 x 256 threads (524288 rows).
// ---------------------------------------------------------------------------
__global__ __launch_bounds__(256) void k_pairbias(
    const float* __restrict__ pairX, const float* __restrict__ wph,
    const float* __restrict__ csum, float* __restrict__ bias)
{
    const int row = blockIdx.x * 256 + threadIdx.x;
    const float* rp = pairX + (size_t)row * CPD;

    float acc[8] = {};
    float sum = 0.f, sumsq = 0.f;
    for (int s = 0; s < 8; ++s) {
        float rr[16];
        *(float4*)&rr[0]  = *(const float4*)(rp + s * 16 + 0);
        *(float4*)&rr[4]  = *(const float4*)(rp + s * 16 + 4);
        *(float4*)&rr[8]  = *(const float4*)(rp + s * 16 + 8);
        *(float4*)&rr[12] = *(const float4*)(rp + s * 16 + 12);
#pragma unroll
        for (int k = 0; k < 16; ++k) { sum += rr[k]; sumsq = fmaf(rr[k], rr[k], sumsq); }
        const float* wp_s = wph + s * 16;
#pragma unroll
        for (int h = 0; h < 8; ++h) {
            const float* w = wp_s + h * 128;   // uniform address -> s_load
#pragma unroll
            for (int k = 0; k < 16; ++k) acc[h] = fmaf(rr[k], w[k], acc[h]);
        }
    }
    const float m = sum * (1.f / 128.f);
    const float inv = rsqrtf(sumsq * (1.f / 128.f) - m * m + 1e-6f);
    const int b = row >> 18;
    const int ij = row & 262143;
    float* bo = bias + ((size_t)b << 21) + ij;
#pragma unroll
    for (int h = 0; h < 8; ++h) {
        float o = inv * (acc[h] - m * csum[h]) + csum[8 + h];
        bo[(size_t)h << 18] = o;
    }
}

// ---------------------------------------------------------------------------
// K3: oriQK = q.k^T (K=24) + bias.  block = (bch, itile of 32 rows). grid=768.
// ---------------------------------------------------------------------------
__global__ __launch_bounds__(256) void k_qkmat(
    const float* __restrict__ q, const float* __restrict__ k,
    const float* __restrict__ bias, float* __restrict__ oriQK)
{
    __shared__ float Kl[512 * 25];   // pad 24->25
    __shared__ float Ql[32 * 25];
    const int tid = threadIdx.x;
    const int bch = blockIdx.x >> 4;       // b*24 + c*8 + h
    const int itile = blockIdx.x & 15;
    const float* kp = k + (size_t)bch * 512 * 24;
    const float* qp = q + (size_t)bch * 512 * 24 + (size_t)itile * 32 * 24;
    for (int idx = tid; idx < 512 * 24; idx += 256) {
        int j = idx / 24, d = idx - j * 24;
        Kl[j * 25 + d] = kp[idx];
    }
    for (int idx = tid; idx < 32 * 24; idx += 256) {
        int i = idx / 24, d = idx - i * 24;
        Ql[i * 25 + d] = qp[idx];
    }
    __syncthreads();

    const int ti = tid >> 4, tj = tid & 15;
    const int b = bch / 24, h = bch & 7;
    const float* biasp = bias + ((size_t)(b * 8 + h) * 512 + itile * 32) * 512;
    float* outp = oriQK + (size_t)bch * 262144 + (size_t)itile * 32 * 512;

    for (int cc = 0; cc < 4; ++cc) {
        float acc[2][8] = {};
        for (int d = 0; d < 24; ++d) {
            float qv[2], kv[8];
#pragma unroll
            for (int r = 0; r < 2; ++r) qv[r] = Ql[(ti * 2 + r) * 25 + d];
#pragma unroll
            for (int u = 0; u < 8; ++u) kv[u] = Kl[(cc * 128 + u * 16 + tj) * 25 + d];
#pragma unroll
            for (int r = 0; r < 2; ++r)
#pragma unroll
                for (int u = 0; u < 8; ++u) acc[r][u] += qv[r] * kv[u];
        }
#pragma unroll
        for (int r = 0; r < 2; ++r) {
            int i = ti * 2 + r;
#pragma unroll
            for (int u = 0; u < 8; ++u) {
                int j = cc * 128 + u * 16 + tj;
                outp[(size_t)i * 512 + j] = acc[r][u] + biasp[(size_t)i * 512 + j];
            }
        }
    }
}

// ---------------------------------------------------------------------------
// K4: 5x5 conv + fused qk/gq epilogue.  grid=512.
// ---------------------------------------------------------------------------
__global__ __launch_bounds__(256) void k_conv(
    const float* __restrict__ oriQK, const float* __restrict__ convW, const float* __restrict__ convB,
    float* __restrict__ qk, float* __restrict__ gq)
{
    __shared__ float tile[24 * 36 * 40];
    __shared__ float wS[4800];
    __shared__ float cbS[8];
    const int tid = threadIdx.x;
    const int bx = blockIdx.x;
    const int b = bx >> 8, rem = bx & 255;
    const int i0 = (rem >> 4) * 32, j0 = (rem & 15) * 32;

    for (int i = tid; i < 4800; i += 256) wS[i] = convW[i];
    if (tid < 8) cbS[tid] = convB[tid] + convB[8 + tid] + convB[16 + tid];
    for (int idx = tid; idx < 24 * 36 * 36; idx += 256) {
        int ch = idx / 1296, r = idx - ch * 1296;
        int ii = r / 36, jj = r - ii * 36;
        int gi = i0 - 2 + ii, gj = j0 - 2 + jj;
        float v = 0.f;
        if ((unsigned)gi < 512u && (unsigned)gj < 512u)
            v = oriQK[((size_t)(b * 24 + ch) << 18) + ((size_t)gi << 9) + gj];
        tile[ch * 1440 + ii * 40 + jj] = v;
    }
    __syncthreads();

    const int jg = tid & 7, ii = tid >> 3;
    const int j4 = jg * 4;
    float acc[4][8] = {};
    for (int c = 0; c < 3; ++c)
        for (int hi = 0; hi < 8; ++hi) {
            const float* tch = &tile[(c * 8 + hi) * 1440];
            const float* wch = &wS[c * 1600 + hi * 25];
#pragma unroll
            for (int kh = 0; kh < 5; ++kh) {
                const float* trow = &tch[(ii + kh) * 40 + j4];
                float v[8];
                *(float4*)&v[0] = *(const float4*)&trow[0];
                *(float4*)&v[4] = *(const float4*)&trow[4];
#pragma unroll
                for (int kw = 0; kw < 5; ++kw) {
#pragma unroll
                    for (int h = 0; h < 8; ++h) {
                        float w = wch[h * 200 + kh * 5 + kw];
                        acc[0][h] += w * v[kw];
                        acc[1][h] += w * v[kw + 1];
                        acc[2][h] += w * v[kw + 2];
                        acc[3][h] += w * v[kw + 3];
                    }
                }
            }
        }

    const int gi = i0 + ii, gj = j0 + j4;
    float* qkb = qk + ((size_t)(b * 24) << 18) + ((size_t)gi << 9) + gj;
    float gqv[4][8];
#pragma unroll
    for (int h = 0; h < 8; ++h) {
        float cv = cbS[h];
        float c0 = acc[0][h] + cv, c1 = acc[1][h] + cv, c2 = acc[2][h] + cv, c3 = acc[3][h] + cv;
        float m0 = 0, m1 = 0, m2 = 0, m3 = 0;
#pragma unroll
        for (int c = 0; c < 3; ++c) {
            const float* tr = &tile[(c * 8 + h) * 1440 + (ii + 2) * 40 + j4 + 2];
            float t0 = tr[0], t1 = tr[1], t2 = tr[2], t3 = tr[3];
            m0 += t0; m1 += t1; m2 += t2; m3 += t3;
            float4 o = make_float4((t0 + c0) * INV_DIV, (t1 + c1) * INV_DIV,
                                   (t2 + c2) * INV_DIV, (t3 + c3) * INV_DIV);
            *(float4*)(qkb + ((size_t)(c * 8 + h) << 18)) = o;
        }
        gqv[0][h] = gelu_exact((m0 * (1.f / 3.f) + c0) * INV_DIV);
        gqv[1][h] = gelu_exact((m1 * (1.f / 3.f) + c1) * INV_DIV);
        gqv[2][h] = gelu_exact((m2 * (1.f / 3.f) + c2) * INV_DIV);
        gqv[3][h] = gelu_exact((m3 * (1.f / 3.f) + c3) * INV_DIV);
    }
    float* gqb = gq + (((size_t)(b * 512 + gi) << 9) + gj) * 8;
#pragma unroll
    for (int jc = 0; jc < 4; ++jc) {
        *(float4*)(gqb + jc * 8)     = make_float4(gqv[jc][0], gqv[jc][1], gqv[jc][2], gqv[jc][3]);
        *(float4*)(gqb + jc * 8 + 4) = make_float4(gqv[jc][4], gqv[jc][5], gqv[jc][6], gqv[jc][7]);
    }
}

// ---------------------------------------------------------------------------
// K5: out2 = gq(8) @ Wpr(8x128) + bpr.  grid=2048, 256 pos/block.
// ---------------------------------------------------------------------------
__global__ __launch_bounds__(256) void k_out2(
    const float* __restrict__ gq, const float* __restrict__ Wpr, const float* __restrict__ bpr,
    float* __restrict__ out2)
{
    __shared__ float WprS[8 * 128];
    __shared__ float bprS[128];
    const int tid = threadIdx.x;
    for (int i = tid; i < 1024; i += 256) WprS[i] = Wpr[i];
    if (tid < 128) bprS[tid] = bpr[tid];
    __syncthreads();

    const int p = (tid & 31) * 4;
    float4 wv[8];
#pragma unroll
    for (int h = 0; h < 8; ++h) wv[h] = *(const float4*)&WprS[h * 128 + p];
    const float4 bv = *(const float4*)&bprS[p];

    size_t pos0 = (size_t)blockIdx.x * 256 + (tid >> 5);
    for (int it = 0; it < 32; ++it) {
        size_t pos = pos0 + it * 8;
        const float4 ga = *(const float4*)(gq + pos * 8);
        const float4 gb = *(const float4*)(gq + pos * 8 + 4);
        float4 o = bv;
        o.x += ga.x * wv[0].x + ga.y * wv[1].x + ga.z * wv[2].x + ga.w * wv[3].x
             + gb.x * wv[4].x + gb.y * wv[5].x + gb.z * wv[6].x + gb.w * wv[7].x;
        o.y += ga.x * wv[0].y + ga.y * wv[1].y + ga.z * wv[2].y + ga.w * wv[3].y
             + gb.x * wv[4].y + gb.y * wv[5].y + gb.z * wv[6].y + gb.w * wv[7].y;
        o.z += ga.x * wv[0].z + ga.y * wv[1].z + ga.z * wv[2].z + ga.w * wv[3].z
             + gb.x * wv[4].z + gb.y * wv[5].z + gb.z * wv[6].z + gb.w * wv[7].z;
        o.w += ga.x * wv[0].w + ga.y * wv[1].w + ga.z * wv[2].w + ga.w * wv[3].w
             + gb.x * wv[4].w + gb.y * wv[5].w + gb.z * wv[6].w + gb.w * wv[7].w;
        *(float4*)(out2 + pos * 128 + p) = o;
    }
}

// ---------------------------------------------------------------------------
// K6: softmax over qk rows + P@V + sigmoid(gate).  wave per row, V in LDS
// (stride 28 -> 16B-aligned float4, bank-slot tiling conflict-free).
// grid=768 (48 bch x 16 itiles of 32 rows).
// ---------------------------------------------------------------------------
__global__ __launch_bounds__(256) void k_softmax_pv(
    const float* __restrict__ qk, const float* __restrict__ v, const float* __restrict__ gate,
    float* __restrict__ houts)
{
    __shared__ float Vl[512 * 28];   // 57.3 KB
    const int tid = threadIdx.x;
    const int bch = blockIdx.x >> 4, itile = blockIdx.x & 15;
    const float* vp = v + (size_t)bch * (512 * 24);
    for (int idx = tid; idx < 512 * 24; idx += 256) {
        int j = idx / 24, d = idx - j * 24;
        Vl[j * 28 + d] = vp[idx];
    }
    __syncthreads();

    const int wid = tid >> 6, lane = tid & 63;
    const int b = bch / 24, c = (bch % 24) >> 3, h = bch & 7;
    for (int rr = 0; rr < 8; ++rr) {
        const int i = itile * 32 + wid * 8 + rr;
        const float* row = qk + ((size_t)bch * 512 + i) * 512;
        float e[8]; float mx = -1e30f;
#pragma unroll
        for (int u = 0; u < 8; ++u) { e[u] = row[lane + 64 * u]; mx = fmaxf(mx, e[u]); }
#pragma unroll
        for (int o = 32; o; o >>= 1) mx = fmaxf(mx, __shfl_xor(mx, o));
        float s = 0.f;
#pragma unroll
        for (int u = 0; u < 8; ++u) { e[u] = __expf(e[u] - mx); s += e[u]; }
#pragma unroll
        for (int o = 32; o; o >>= 1) s += __shfl_xor(s, o);
        float inv = 1.f / s;

        float4 a4[6] = {};
#pragma unroll
        for (int u = 0; u < 8; ++u) {
            float p = e[u] * inv;
            const float* vr = &Vl[(u * 64 + lane) * 28];
#pragma unroll
            for (int k = 0; k < 6; ++k) {
                float4 vv = *(const float4*)(vr + 4 * k);
                a4[k].x = fmaf(p, vv.x, a4[k].x);
                a4[k].y = fmaf(p, vv.y, a4[k].y);
                a4[k].z = fmaf(p, vv.z, a4[k].z);
                a4[k].w = fmaf(p, vv.w, a4[k].w);
            }
        }
        // butterfly allreduce over 64 lanes
#pragma unroll
        for (int o = 32; o; o >>= 1) {
#pragma unroll
            for (int k = 0; k < 6; ++k) {
                a4[k].x += __shfl_xor(a4[k].x, o);
                a4[k].y += __shfl_xor(a4[k].y, o);
                a4[k].z += __shfl_xor(a4[k].z, o);
                a4[k].w += __shfl_xor(a4[k].w, o);
            }
        }
        // epilogue: compute gated output (redundant on all lanes), lane0 stores
        const float* gp = gate + ((size_t)bch * 512 + i) * 24;
        float* op = houts + ((size_t)(b * 512 + i)) * 576 + c * 192 + h * 24;
#pragma unroll
        for (int k = 0; k < 6; ++k) {
            float4 g4 = *(const float4*)(gp + 4 * k);
            float4 o4;
            o4.x = a4[k].x / (1.f + __expf(-g4.x));
            o4.y = a4[k].y / (1.f + __expf(-g4.y));
            o4.z = a4[k].z / (1.f + __expf(-g4.z));
            o4.w = a4[k].w / (1.f + __expf(-g4.w));
            if (lane == 0) *(float4*)(op + 4 * k) = o4;
        }
    }
}

// ---------------------------------------------------------------------------
// K7: out1 = houts @ Wo + bo + x*g.  Tiled GEMM: 32x64 tile, BK=32, grid=288.
// ---------------------------------------------------------------------------
__global__ __launch_bounds__(256) void k_out1(
    const float* __restrict__ houts, const float* __restrict__ Wo, const float* __restrict__ bo,
    const float* __restrict__ x, const float* __restrict__ gsc,
    float* __restrict__ out1)
{
    __shared__ float As[32 * 33];
    __shared__ float Bs[32 * 64];
    const int tid = threadIdx.x;
    const int mt = blockIdx.x / 9, nt = blockIdx.x % 9;
    const int m0 = mt * 32, n0 = nt * 64;
    const int tn = tid & 15, tm = tid >> 4;
    float acc[2][4] = {};

    for (int kk = 0; kk < 576; kk += 32) {
        {
            int idx = tid;
#pragma unroll
            for (int i = 0; i < 4; ++i, idx += 256) {
                int k2 = idx & 31, m = idx >> 5;
                As[m * 33 + k2] = houts[(size_t)(m0 + m) * 576 + kk + k2];
            }
        }
        {
            int idx = tid;
#pragma unroll
            for (int i = 0; i < 8; ++i, idx += 256) {
                int n = idx & 63, k2 = idx >> 6;
                Bs[k2 * 64 + n] = Wo[(size_t)(kk + k2) * 576 + n0 + n];
            }
        }
        __syncthreads();
#pragma unroll
        for (int k2 = 0; k2 < 32; ++k2) {
            float a0 = As[(tm * 2 + 0) * 33 + k2];
            float a1 = As[(tm * 2 + 1) * 33 + k2];
            const float4 bv = *(const float4*)&Bs[k2 * 64 + tn * 4];
            acc[0][0] += a0 * bv.x; acc[0][1] += a0 * bv.y; acc[0][2] += a0 * bv.z; acc[0][3] += a0 * bv.w;
            acc[1][0] += a1 * bv.x; acc[1][1] += a1 * bv.y; acc[1][2] += a1 * bv.z; acc[1][3] += a1 * bv.w;
        }
        __syncthreads();
    }

    const float gv = gsc[0];
    const float4 b4 = *(const float4*)&bo[n0 + tn * 4];
#pragma unroll
    for (int r = 0; r < 2; ++r) {
        size_t row = (size_t)m0 + tm * 2 + r;
        size_t off = row * 576 + n0 + tn * 4;
        const float4 x4 = *(const float4*)&x[off];
        float4 o;
        o.x = acc[r][0] + b4.x + x4.x * gv;
        o.y = acc[r][1] + b4.y + x4.y * gv;
        o.z = acc[r][2] + b4.z + x4.z * gv;
        o.w = acc[r][3] + b4.w + x4.w * gv;
        *(float4*)&out1[off] = o;
    }
}

// ---------------------------------------------------------------------------
extern "C" void kernel_launch(void* const* d_in, const int* in_sizes, int n_in,
                              void* d_out, int out_size, void* d_ws, size_t ws_size,
                              hipStream_t stream) {
    const float* x     = (const float*)d_in[0];
    const float* pairX = (const float*)d_in[1];
    const float* g     = (const float*)d_in[2];
    const float* ln1w  = (const float*)d_in[3];
    const float* ln1b  = (const float*)d_in[4];
    const float* ln2w  = (const float*)d_in[5];
    const float* ln2b  = (const float*)d_in[6];
    const float* Wq    = (const float*)d_in[7];
    const float* bq    = (const float*)d_in[8];
    const float* Wk    = (const float*)d_in[9];
    const float* bk    = (const float*)d_in[10];
    const float* Wv    = (const float*)d_in[11];
    const float* bv    = (const float*)d_in[12];
    const float* Wg    = (const float*)d_in[13];
    const float* bg    = (const float*)d_in[14];
    const float* convW = (const float*)d_in[15];
    const float* convB = (const float*)d_in[16];
    const float* Wp    = (const float*)d_in[17];
    const float* bp    = (const float*)d_in[18];
    const float* Wpr   = (const float*)d_in[19];
    const float* bpr   = (const float*)d_in[20];
    const float* Wo    = (const float*)d_in[21];
    const float* bo    = (const float*)d_in[22];

    float* ws   = (float*)d_ws;
    float* q    = ws + OFF_Q;
    float* k    = ws + OFF_K;
    float* vv   = ws + OFF_V;
    float* gt   = ws + OFF_G;
    float* bias = ws + OFF_BIAS;
    float* gq   = ws + OFF_BIAS;   // alias: bias dead after k_qkmat
    float* ori  = ws + OFF_ORI;
    float* qkb  = ws + OFF_QK;
    float* hout = ws + OFF_H;
    float* wph  = ws + OFF_WPH;
    float* csum = ws + OFF_CS;

    float* out1 = (float*)d_out;
    float* out2 = out1 + 589824;

    k_prep<<<dim3(1), dim3(256), 0, stream>>>(ln2w, ln2b, Wp, bp, wph, csum);
    k_ln_proj<<<dim3(1024), dim3(256), 0, stream>>>(x, ln1w, ln1b, Wq, bq, Wk, bk, Wv, bv, Wg, bg,
                                                    q, k, vv, gt);
    k_pairbias<<<dim3(2048), dim3(256), 0, stream>>>(pairX, wph, csum, bias);
    k_qkmat<<<dim3(768), dim3(256), 0, stream>>>(q, k, bias, ori);
    k_conv<<<dim3(512), dim3(256), 0, stream>>>(ori, convW, convB, qkb, gq);
    k_out2<<<dim3(2048), dim3(256), 0, stream>>>(gq, Wpr, bpr, out2);
    k_softmax_pv<<<dim3(768), dim3(256), 0, stream>>>(qkb, vv, gt, hout);
    k_out1<<<dim3(288), dim3(256), 0, stream>>>(hout, Wo, bo, x, g, out1);
}

// Round 5
// 557.206 us; speedup vs baseline: 1.9093x; 1.1383x over previous
//
#include <hip/hip_runtime.h>
#include <hip/hip_bf16.h>

// Problem constants
#define BDIM 2
#define LDIM 512
#define CDIM 576
#define HDIM 8
#define CPD  128
#define DK3  24
#define INV_DIV 0.117851130197757920f   // 1/sqrt(72)

// Workspace layout (floats).
static constexpr size_t OFF_Q    = 0;                       // [B,3,H,L,24] 589824
static constexpr size_t OFF_K    = 589824;
static constexpr size_t OFF_V    = 1179648;
static constexpr size_t OFF_G    = 1769472;
static constexpr size_t OFF_BIAS = 2359296;                 // [B,H,L,L] 4194304 ; reused as gq [B,L,L,H] after k_qkmat
static constexpr size_t OFF_ORI  = OFF_BIAS + 4194304;      // [B,3,H,L,L] 12582912
static constexpr size_t OFF_QK   = OFF_ORI + 12582912;      // [B,3,H,L,L] 12582912
static constexpr size_t OFF_H    = OFF_QK + 12582912;       // [B*L,576]   589824
static constexpr size_t OFF_WPH  = OFF_H + 589824;          // [8][128] = 1024
static constexpr size_t OFF_CS   = OFF_WPH + 1024;          // [16]: colsum[8], cbp[8]

__device__ __forceinline__ float gelu_exact(float v) {
    return 0.5f * v * (1.f + erff(v * 0.70710678118654752f));
}

// ---------------------------------------------------------------------------
// K0: prep for pairbias.  wph[h][d] = ln2w[d]*Wp[d][h]; colsum/cbp folds.
// ---------------------------------------------------------------------------
__global__ __launch_bounds__(256) void k_prep(
    const float* __restrict__ ln2w, const float* __restrict__ ln2b,
    const float* __restrict__ Wp, const float* __restrict__ bp,
    float* __restrict__ wph, float* __restrict__ csum)
{
    const int tid = threadIdx.x;
    for (int i = tid; i < 1024; i += 256) {
        int h = i >> 7, d = i & 127;
        wph[i] = ln2w[d] * Wp[d * 8 + h];
    }
    __syncthreads();
    if (tid < 16) {
        int h = tid & 7;
        float s = 0.f;
        if (tid < 8) {
            for (int d = 0; d < 128; ++d) s += wph[h * 128 + d];
            csum[h] = s;
        } else {
            for (int d = 0; d < 128; ++d) s += ln2b[d] * Wp[d * 8 + h];
            csum[8 + h] = s + bp[h];
        }
    }
}

// ---------------------------------------------------------------------------
// K1: LN(x) + one of q/k/v/gate projection per block.  grid=1024.
// ---------------------------------------------------------------------------
__global__ __launch_bounds__(256) void k_ln_proj(
    const float* __restrict__ x, const float* __restrict__ ln1w, const float* __restrict__ ln1b,
    const float* __restrict__ Wq, const float* __restrict__ bq,
    const float* __restrict__ Wk, const float* __restrict__ bk,
    const float* __restrict__ Wv, const float* __restrict__ bv,
    const float* __restrict__ Wg, const float* __restrict__ bg,
    float* __restrict__ qo, float* __restrict__ ko, float* __restrict__ vo, float* __restrict__ go)
{
    __shared__ float xn[4 * 576];
    const int tid = threadIdx.x;
    const int wid = tid >> 6, lane = tid & 63;
    const int mi = blockIdx.x & 3;
    const int row0 = (blockIdx.x >> 2) * 4;   // b*512 + l ; never straddles b

    {   // each wave LNs one row (576 = 64*9)
        const float* xr = x + (size_t)(row0 + wid) * CDIM;
        float vals[9]; float s = 0.f, sq = 0.f;
#pragma unroll
        for (int u = 0; u < 9; ++u) {
            float v = xr[lane + 64 * u];
            vals[u] = v; s += v; sq += v * v;
        }
#pragma unroll
        for (int o = 32; o; o >>= 1) { s += __shfl_xor(s, o); sq += __shfl_xor(sq, o); }
        float m = s * (1.f / 576.f);
        float inv = rsqrtf(sq * (1.f / 576.f) - m * m + 1e-6f);
#pragma unroll
        for (int u = 0; u < 9; ++u) {
            int idx = lane + 64 * u;
            xn[wid * 576 + idx] = (vals[u] - m) * inv * ln1w[idx] + ln1b[idx];
        }
    }
    __syncthreads();

    const float* W  = mi == 0 ? Wq : mi == 1 ? Wk : mi == 2 ? Wv : Wg;
    const float* bb = mi == 0 ? bq : mi == 1 ? bk : mi == 2 ? bv : bg;
    float* op       = mi == 0 ? qo : mi == 1 ? ko : mi == 2 ? vo : go;
    const int b = row0 >> 9, l = row0 & 511;

    const int j0 = tid, j1 = tid + 256;
    const int g0 = j0 / 192, g1 = j1 / 192;          // g2 = 2
    const int q0 = j0 - 192 * g0, q1 = j1 - 192 * g1, q2 = tid + 128;
    const bool has2 = (tid < 64);
    float acc0[4] = {}, acc1[4] = {}, acc2[4] = {};
    for (int d = 0; d < 192; ++d) {
        float w0 = W[(size_t)d * 192 + q0];
        float w1 = W[(size_t)d * 192 + q1];
        float x0 = xn[g0 * 192 + d],            x0b = xn[576 + g0 * 192 + d];
        float x0c = xn[1152 + g0 * 192 + d],    x0d = xn[1728 + g0 * 192 + d];
        float x1 = xn[g1 * 192 + d],            x1b = xn[576 + g1 * 192 + d];
        float x1c = xn[1152 + g1 * 192 + d],    x1d = xn[1728 + g1 * 192 + d];
        acc0[0] += x0 * w0; acc0[1] += x0b * w0; acc0[2] += x0c * w0; acc0[3] += x0d * w0;
        acc1[0] += x1 * w1; acc1[1] += x1b * w1; acc1[2] += x1c * w1; acc1[3] += x1d * w1;
        if (has2) {
            float w2 = W[(size_t)d * 192 + q2];
            float x2 = xn[384 + d], x2b = xn[576 + 384 + d];
            float x2c = xn[1152 + 384 + d], x2d = xn[1728 + 384 + d];
            acc2[0] += x2 * w2; acc2[1] += x2b * w2; acc2[2] += x2c * w2; acc2[3] += x2d * w2;
        }
    }
    {
        int h = q0 / 24, d24 = q0 % 24;
        float bj = bb[q0];
        float* o = op + ((((size_t)b * 3 + g0) * HDIM + h) * LDIM + l) * DK3 + d24;
#pragma unroll
        for (int r = 0; r < 4; ++r) o[r * DK3] = acc0[r] + bj;
    }
    {
        int h = q1 / 24, d24 = q1 % 24;
        float bj = bb[q1];
        float* o = op + ((((size_t)b * 3 + g1) * HDIM + h) * LDIM + l) * DK3 + d24;
#pragma unroll
        for (int r = 0; r < 4; ++r) o[r * DK3] = acc1[r] + bj;
    }
    if (has2) {
        int h = q2 / 24, d24 = q2 % 24;
        float bj = bb[q2];
        float* o = op + ((((size_t)b * 3 + 2) * HDIM + h) * LDIM + l) * DK3 + d24;
#pragma unroll
        for (int r = 0; r < 4; ++r) o[r * DK3] = acc2[r] + bj;
    }
}

// ---------------------------------------------------------------------------
// K2: pairBias.  ONE THREAD = ONE (b,i,j) ROW.  LN folded analytically.
// grid=2048 x 256 threads (524288 rows).
// ---------------------------------------------------------------------------
__global__ __launch_bounds__(256) void k_pairbias(
    const float* __restrict__ pairX, const float* __restrict__ wph,
    const float* __restrict__ csum, float* __restrict__ bias)
{
    const int row = blockIdx.x * 256 + threadIdx.x;
    const float* rp = pairX + (size_t)row * CPD;

    float acc[8] = {};
    float sum = 0.f, sumsq = 0.f;
    for (int s = 0; s < 8; ++s) {
        float rr[16];
        *(float4*)&rr[0]  = *(const float4*)(rp + s * 16 + 0);
        *(float4*)&rr[4]  = *(const float4*)(rp + s * 16 + 4);
        *(float4*)&rr[8]  = *(const float4*)(rp + s * 16 + 8);
        *(float4*)&rr[12] = *(const float4*)(rp + s * 16 + 12);
#pragma unroll
        for (int k = 0; k < 16; ++k) { sum += rr[k]; sumsq = fmaf(rr[k], rr[k], sumsq); }
        const float* wp_s = wph + s * 16;
#pragma unroll
        for (int h = 0; h < 8; ++h) {
            const float* w = wp_s + h * 128;   // uniform address -> s_load
#pragma unroll
            for (int k = 0; k < 16; ++k) acc[h] = fmaf(rr[k], w[k], acc[h]);
        }
    }
    const float m = sum * (1.f / 128.f);
    const float inv = rsqrtf(sumsq * (1.f / 128.f) - m * m + 1e-6f);
    const int b = row >> 18;
    const int ij = row & 262143;
    float* bo = bias + ((size_t)b << 21) + ij;
#pragma unroll
    for (int h = 0; h < 8; ++h) {
        float o = inv * (acc[h] - m * csum[h]) + csum[8 + h];
        bo[(size_t)h << 18] = o;
    }
}

// ---------------------------------------------------------------------------
// K3: oriQK = q.k^T (K=24) + bias.  block = (bch, itile of 32 rows). grid=768.
// ---------------------------------------------------------------------------
__global__ __launch_bounds__(256) void k_qkmat(
    const float* __restrict__ q, const float* __restrict__ k,
    const float* __restrict__ bias, float* __restrict__ oriQK)
{
    __shared__ float Kl[512 * 25];   // pad 24->25
    __shared__ float Ql[32 * 25];
    const int tid = threadIdx.x;
    const int bch = blockIdx.x >> 4;       // b*24 + c*8 + h
    const int itile = blockIdx.x & 15;
    const float* kp = k + (size_t)bch * 512 * 24;
    const float* qp = q + (size_t)bch * 512 * 24 + (size_t)itile * 32 * 24;
    for (int idx = tid; idx < 512 * 24; idx += 256) {
        int j = idx / 24, d = idx - j * 24;
        Kl[j * 25 + d] = kp[idx];
    }
    for (int idx = tid; idx < 32 * 24; idx += 256) {
        int i = idx / 24, d = idx - i * 24;
        Ql[i * 25 + d] = qp[idx];
    }
    __syncthreads();

    const int ti = tid >> 4, tj = tid & 15;
    const int b = bch / 24, h = bch & 7;
    const float* biasp = bias + ((size_t)(b * 8 + h) * 512 + itile * 32) * 512;
    float* outp = oriQK + (size_t)bch * 262144 + (size_t)itile * 32 * 512;

    for (int cc = 0; cc < 4; ++cc) {
        float acc[2][8] = {};
        for (int d = 0; d < 24; ++d) {
            float qv[2], kv[8];
#pragma unroll
            for (int r = 0; r < 2; ++r) qv[r] = Ql[(ti * 2 + r) * 25 + d];
#pragma unroll
            for (int u = 0; u < 8; ++u) kv[u] = Kl[(cc * 128 + u * 16 + tj) * 25 + d];
#pragma unroll
            for (int r = 0; r < 2; ++r)
#pragma unroll
                for (int u = 0; u < 8; ++u) acc[r][u] += qv[r] * kv[u];
        }
#pragma unroll
        for (int r = 0; r < 2; ++r) {
            int i = ti * 2 + r;
#pragma unroll
            for (int u = 0; u < 8; ++u) {
                int j = cc * 128 + u * 16 + tj;
                outp[(size_t)i * 512 + j] = acc[r][u] + biasp[(size_t)i * 512 + j];
            }
        }
    }
}

// ---------------------------------------------------------------------------
// K4: 5x5 conv + fused qk/gq epilogue.  grid=512.
// v2: c-chunked staging (8 ch at a time, 46 KB tile + 6.4 KB weights ->
// 52.5 KB LDS -> 3 blocks/CU capacity).  Weights staged transposed
// [hi][kh][kw][h] so inner loop reads 2 uniform b128 per kw.  Epilogue
// re-reads center values from global (L2-hot).
// ---------------------------------------------------------------------------
__global__ __launch_bounds__(256, 3) void k_conv(
    const float* __restrict__ oriQK, const float* __restrict__ convW, const float* __restrict__ convB,
    float* __restrict__ qk, float* __restrict__ gq)
{
    __shared__ float tile[8 * 36 * 40];   // 46080 B, per-branch
    __shared__ float wT[1600];            // [hi][kh][kw][h] for current branch
    __shared__ float cbS[8];
    const int tid = threadIdx.x;
    const int bx = blockIdx.x;
    const int b = bx >> 8, rem = bx & 255;
    const int i0 = (rem >> 4) * 32, j0 = (rem & 15) * 32;

    if (tid < 8) cbS[tid] = convB[tid] + convB[8 + tid] + convB[16 + tid];

    const int jg = tid & 7, ii = tid >> 3;   // 8 col-groups x 32 rows
    const int j4 = jg * 4;
    float acc[8][4] = {};                    // [h_out][jcol]

    for (int c = 0; c < 3; ++c) {
        __syncthreads();   // protect previous iteration's reads
        // stage weights transposed: wT[((hi*5+kh)*5+kw)*8 + h] = convW[c][h][hi][kh][kw]
        for (int i = tid; i < 1600; i += 256) {
            int h = i & 7, rest = i >> 3;
            int kw = rest % 5, kh = (rest / 5) % 5, hi = rest / 25;
            wT[i] = convW[c * 1600 + h * 200 + hi * 25 + kh * 5 + kw];
        }
        // stage 8 channels of the 36x36 halo tile
        for (int idx = tid; idx < 8 * 1296; idx += 256) {
            int ch = idx >> 10 < 8 ? idx / 1296 : 7;   // plain div; compiler magic-muls
            ch = idx / 1296;
            int r = idx - ch * 1296;
            int iw = r / 36, jw = r - iw * 36;
            int gi = i0 - 2 + iw, gj = j0 - 2 + jw;
            float v = 0.f;
            if ((unsigned)gi < 512u && (unsigned)gj < 512u)
                v = oriQK[((size_t)(b * 24 + c * 8 + ch) << 18) + ((size_t)gi << 9) + gj];
            tile[ch * 1440 + iw * 40 + jw] = v;
        }
        __syncthreads();

        for (int hi = 0; hi < 8; ++hi) {
            const float* tch = &tile[hi * 1440];
            const float* wch = &wT[hi * 200];
#pragma unroll
            for (int kh = 0; kh < 5; ++kh) {
                const float* trow = &tch[(ii + kh) * 40 + j4];
                float v[8];
                *(float4*)&v[0] = *(const float4*)&trow[0];
                *(float4*)&v[4] = *(const float4*)&trow[4];
#pragma unroll
                for (int kw = 0; kw < 5; ++kw) {
                    const float4 wA = *(const float4*)&wch[(kh * 5 + kw) * 8];
                    const float4 wB = *(const float4*)&wch[(kh * 5 + kw) * 8 + 4];
#pragma unroll
                    for (int j = 0; j < 4; ++j) {
                        float vv = v[kw + j];
                        acc[0][j] = fmaf(wA.x, vv, acc[0][j]);
                        acc[1][j] = fmaf(wA.y, vv, acc[1][j]);
                        acc[2][j] = fmaf(wA.z, vv, acc[2][j]);
                        acc[3][j] = fmaf(wA.w, vv, acc[3][j]);
                        acc[4][j] = fmaf(wB.x, vv, acc[4][j]);
                        acc[5][j] = fmaf(wB.y, vv, acc[5][j]);
                        acc[6][j] = fmaf(wB.z, vv, acc[6][j]);
                        acc[7][j] = fmaf(wB.w, vv, acc[7][j]);
                    }
                }
            }
        }
    }

    // epilogue: centers re-read from global (L2-hot), write qk and gq
    const int gi = i0 + ii, gj = j0 + j4;
    const float* orib = oriQK + ((size_t)(b * 24) << 18) + ((size_t)gi << 9) + gj;
    float* qkb = qk + ((size_t)(b * 24) << 18) + ((size_t)gi << 9) + gj;
    float gqv[4][8];
#pragma unroll
    for (int h = 0; h < 8; ++h) {
        float cv = cbS[h];
        float c0 = acc[h][0] + cv, c1 = acc[h][1] + cv, c2 = acc[h][2] + cv, c3 = acc[h][3] + cv;
        float m0 = 0, m1 = 0, m2 = 0, m3 = 0;
#pragma unroll
        for (int c = 0; c < 3; ++c) {
            const float4 t = *(const float4*)(orib + ((size_t)(c * 8 + h) << 18));
            m0 += t.x; m1 += t.y; m2 += t.z; m3 += t.w;
            float4 o = make_float4((t.x + c0) * INV_DIV, (t.y + c1) * INV_DIV,
                                   (t.z + c2) * INV_DIV, (t.w + c3) * INV_DIV);
            *(float4*)(qkb + ((size_t)(c * 8 + h) << 18)) = o;
        }
        gqv[0][h] = gelu_exact((m0 * (1.f / 3.f) + c0) * INV_DIV);
        gqv[1][h] = gelu_exact((m1 * (1.f / 3.f) + c1) * INV_DIV);
        gqv[2][h] = gelu_exact((m2 * (1.f / 3.f) + c2) * INV_DIV);
        gqv[3][h] = gelu_exact((m3 * (1.f / 3.f) + c3) * INV_DIV);
    }
    float* gqb = gq + (((size_t)(b * 512 + gi) << 9) + gj) * 8;
#pragma unroll
    for (int jc = 0; jc < 4; ++jc) {
        *(float4*)(gqb + jc * 8)     = make_float4(gqv[jc][0], gqv[jc][1], gqv[jc][2], gqv[jc][3]);
        *(float4*)(gqb + jc * 8 + 4) = make_float4(gqv[jc][4], gqv[jc][5], gqv[jc][6], gqv[jc][7]);
    }
}

// ---------------------------------------------------------------------------
// K5: out2 = gq(8) @ Wpr(8x128) + bpr.  grid=2048, 256 pos/block.
// ---------------------------------------------------------------------------
__global__ __launch_bounds__(256) void k_out2(
    const float* __restrict__ gq, const float* __restrict__ Wpr, const float* __restrict__ bpr,
    float* __restrict__ out2)
{
    __shared__ float WprS[8 * 128];
    __shared__ float bprS[128];
    const int tid = threadIdx.x;
    for (int i = tid; i < 1024; i += 256) WprS[i] = Wpr[i];
    if (tid < 128) bprS[tid] = bpr[tid];
    __syncthreads();

    const int p = (tid & 31) * 4;
    float4 wv[8];
#pragma unroll
    for (int h = 0; h < 8; ++h) wv[h] = *(const float4*)&WprS[h * 128 + p];
    const float4 bv = *(const float4*)&bprS[p];

    size_t pos0 = (size_t)blockIdx.x * 256 + (tid >> 5);
    for (int it = 0; it < 32; ++it) {
        size_t pos = pos0 + it * 8;
        const float4 ga = *(const float4*)(gq + pos * 8);
        const float4 gb = *(const float4*)(gq + pos * 8 + 4);
        float4 o = bv;
        o.x += ga.x * wv[0].x + ga.y * wv[1].x + ga.z * wv[2].x + ga.w * wv[3].x
             + gb.x * wv[4].x + gb.y * wv[5].x + gb.z * wv[6].x + gb.w * wv[7].x;
        o.y += ga.x * wv[0].y + ga.y * wv[1].y + ga.z * wv[2].y + ga.w * wv[3].y
             + gb.x * wv[4].y + gb.y * wv[5].y + gb.z * wv[6].y + gb.w * wv[7].y;
        o.z += ga.x * wv[0].z + ga.y * wv[1].z + ga.z * wv[2].z + ga.w * wv[3].z
             + gb.x * wv[4].z + gb.y * wv[5].z + gb.z * wv[6].z + gb.w * wv[7].z;
        o.w += ga.x * wv[0].w + ga.y * wv[1].w + ga.z * wv[2].w + ga.w * wv[3].w
             + gb.x * wv[4].w + gb.y * wv[5].w + gb.z * wv[6].w + gb.w * wv[7].w;
        *(float4*)(out2 + pos * 128 + p) = o;
    }
}

// ---------------------------------------------------------------------------
// K6: softmax over qk rows + P@V + sigmoid(gate).  wave per row, V in LDS
// (stride 28).  grid=768 (48 bch x 16 itiles of 32 rows).
// ---------------------------------------------------------------------------
__global__ __launch_bounds__(256) void k_softmax_pv(
    const float* __restrict__ qk, const float* __restrict__ v, const float* __restrict__ gate,
    float* __restrict__ houts)
{
    __shared__ float Vl[512 * 28];   // 57.3 KB
    const int tid = threadIdx.x;
    const int bch = blockIdx.x >> 4, itile = blockIdx.x & 15;
    const float* vp = v + (size_t)bch * (512 * 24);
    for (int idx = tid; idx < 512 * 24; idx += 256) {
        int j = idx / 24, d = idx - j * 24;
        Vl[j * 28 + d] = vp[idx];
    }
    __syncthreads();

    const int wid = tid >> 6, lane = tid & 63;
    const int b = bch / 24, c = (bch % 24) >> 3, h = bch & 7;
    for (int rr = 0; rr < 8; ++rr) {
        const int i = itile * 32 + wid * 8 + rr;
        const float* row = qk + ((size_t)bch * 512 + i) * 512;
        float e[8]; float mx = -1e30f;
#pragma unroll
        for (int u = 0; u < 8; ++u) { e[u] = row[lane + 64 * u]; mx = fmaxf(mx, e[u]); }
#pragma unroll
        for (int o = 32; o; o >>= 1) mx = fmaxf(mx, __shfl_xor(mx, o));
        float s = 0.f;
#pragma unroll
        for (int u = 0; u < 8; ++u) { e[u] = __expf(e[u] - mx); s += e[u]; }
#pragma unroll
        for (int o = 32; o; o >>= 1) s += __shfl_xor(s, o);
        float inv = 1.f / s;

        float4 a4[6] = {};
#pragma unroll
        for (int u = 0; u < 8; ++u) {
            float p = e[u] * inv;
            const float* vr = &Vl[(u * 64 + lane) * 28];
#pragma unroll
            for (int k = 0; k < 6; ++k) {
                float4 vv = *(const float4*)(vr + 4 * k);
                a4[k].x = fmaf(p, vv.x, a4[k].x);
                a4[k].y = fmaf(p, vv.y, a4[k].y);
                a4[k].z = fmaf(p, vv.z, a4[k].z);
                a4[k].w = fmaf(p, vv.w, a4[k].w);
            }
        }
#pragma unroll
        for (int o = 32; o; o >>= 1) {
#pragma unroll
            for (int k = 0; k < 6; ++k) {
                a4[k].x += __shfl_xor(a4[k].x, o);
                a4[k].y += __shfl_xor(a4[k].y, o);
                a4[k].z += __shfl_xor(a4[k].z, o);
                a4[k].w += __shfl_xor(a4[k].w, o);
            }
        }
        const float* gp = gate + ((size_t)bch * 512 + i) * 24;
        float* op = houts + ((size_t)(b * 512 + i)) * 576 + c * 192 + h * 24;
#pragma unroll
        for (int k = 0; k < 6; ++k) {
            float4 g4 = *(const float4*)(gp + 4 * k);
            float4 o4;
            o4.x = a4[k].x / (1.f + __expf(-g4.x));
            o4.y = a4[k].y / (1.f + __expf(-g4.y));
            o4.z = a4[k].z / (1.f + __expf(-g4.z));
            o4.w = a4[k].w / (1.f + __expf(-g4.w));
            if (lane == 0) *(float4*)(op + 4 * k) = o4;
        }
    }
}

// ---------------------------------------------------------------------------
// K7: out1 = houts @ Wo + bo + x*g.  Tiled GEMM: 32x64 tile, BK=32, grid=288.
// ---------------------------------------------------------------------------
__global__ __launch_bounds__(256) void k_out1(
    const float* __restrict__ houts, const float* __restrict__ Wo, const float* __restrict__ bo,
    const float* __restrict__ x, const float* __restrict__ gsc,
    float* __restrict__ out1)
{
    __shared__ float As[32 * 33];
    __shared__ float Bs[32 * 64];
    const int tid = threadIdx.x;
    const int mt = blockIdx.x / 9, nt = blockIdx.x % 9;
    const int m0 = mt * 32, n0 = nt * 64;
    const int tn = tid & 15, tm = tid >> 4;
    float acc[2][4] = {};

    for (int kk = 0; kk < 576; kk += 32) {
        {
            int idx = tid;
#pragma unroll
            for (int i = 0; i < 4; ++i, idx += 256) {
                int k2 = idx & 31, m = idx >> 5;
                As[m * 33 + k2] = houts[(size_t)(m0 + m) * 576 + kk + k2];
            }
        }
        {
            int idx = tid;
#pragma unroll
            for (int i = 0; i < 8; ++i, idx += 256) {
                int n = idx & 63, k2 = idx >> 6;
                Bs[k2 * 64 + n] = Wo[(size_t)(kk + k2) * 576 + n0 + n];
            }
        }
        __syncthreads();
#pragma unroll
        for (int k2 = 0; k2 < 32; ++k2) {
            float a0 = As[(tm * 2 + 0) * 33 + k2];
            float a1 = As[(tm * 2 + 1) * 33 + k2];
            const float4 bv = *(const float4*)&Bs[k2 * 64 + tn * 4];
            acc[0][0] += a0 * bv.x; acc[0][1] += a0 * bv.y; acc[0][2] += a0 * bv.z; acc[0][3] += a0 * bv.w;
            acc[1][0] += a1 * bv.x; acc[1][1] += a1 * bv.y; acc[1][2] += a1 * bv.z; acc[1][3] += a1 * bv.w;
        }
        __syncthreads();
    }

    const float gv = gsc[0];
    const float4 b4 = *(const float4*)&bo[n0 + tn * 4];
#pragma unroll
    for (int r = 0; r < 2; ++r) {
        size_t row = (size_t)m0 + tm * 2 + r;
        size_t off = row * 576 + n0 + tn * 4;
        const float4 x4 = *(const float4*)&x[off];
        float4 o;
        o.x = acc[r][0] + b4.x + x4.x * gv;
        o.y = acc[r][1] + b4.y + x4.y * gv;
        o.z = acc[r][2] + b4.z + x4.z * gv;
        o.w = acc[r][3] + b4.w + x4.w * gv;
        *(float4*)&out1[off] = o;
    }
}

// ---------------------------------------------------------------------------
extern "C" void kernel_launch(void* const* d_in, const int* in_sizes, int n_in,
                              void* d_out, int out_size, void* d_ws, size_t ws_size,
                              hipStream_t stream) {
    const float* x     = (const float*)d_in[0];
    const float* pairX = (const float*)d_in[1];
    const float* g     = (const float*)d_in[2];
    const float* ln1w  = (const float*)d_in[3];
    const float* ln1b  = (const float*)d_in[4];
    const float* ln2w  = (const float*)d_in[5];
    const float* ln2b  = (const float*)d_in[6];
    const float* Wq    = (const float*)d_in[7];
    const float* bq    = (const float*)d_in[8];
    const float* Wk    = (const float*)d_in[9];
    const float* bk    = (const float*)d_in[10];
    const float* Wv    = (const float*)d_in[11];
    const float* bv    = (const float*)d_in[12];
    const float* Wg    = (const float*)d_in[13];
    const float* bg    = (const float*)d_in[14];
    const float* convW = (const float*)d_in[15];
    const float* convB = (const float*)d_in[16];
    const float* Wp    = (const float*)d_in[17];
    const float* bp    = (const float*)d_in[18];
    const float* Wpr   = (const float*)d_in[19];
    const float* bpr   = (const float*)d_in[20];
    const float* Wo    = (const float*)d_in[21];
    const float* bo    = (const float*)d_in[22];

    float* ws   = (float*)d_ws;
    float* q    = ws + OFF_Q;
    float* k    = ws + OFF_K;
    float* vv   = ws + OFF_V;
    float* gt   = ws + OFF_G;
    float* bias = ws + OFF_BIAS;
    float* gq   = ws + OFF_BIAS;   // alias: bias dead after k_qkmat
    float* ori  = ws + OFF_ORI;
    float* qkb  = ws + OFF_QK;
    float* hout = ws + OFF_H;
    float* wph  = ws + OFF_WPH;
    float* csum = ws + OFF_CS;

    float* out1 = (float*)d_out;
    float* out2 = out1 + 589824;

    k_prep<<<dim3(1), dim3(256), 0, stream>>>(ln2w, ln2b, Wp, bp, wph, csum);
    k_ln_proj<<<dim3(1024), dim3(256), 0, stream>>>(x, ln1w, ln1b, Wq, bq, Wk, bk, Wv, bv, Wg, bg,
                                                    q, k, vv, gt);
    k_pairbias<<<dim3(2048), dim3(256), 0, stream>>>(pairX, wph, csum, bias);
    k_qkmat<<<dim3(768), dim3(256), 0, stream>>>(q, k, bias, ori);
    k_conv<<<dim3(512), dim3(256), 0, stream>>>(ori, convW, convB, qkb, gq);
    k_out2<<<dim3(2048), dim3(256), 0, stream>>>(gq, Wpr, bpr, out2);
    k_softmax_pv<<<dim3(768), dim3(256), 0, stream>>>(qkb, vv, gt, hout);
    k_out1<<<dim3(288), dim3(256), 0, stream>>>(hout, Wo, bo, x, g, out1);
}

// Round 6
// 539.674 us; speedup vs baseline: 1.9713x; 1.0325x over previous
//
#include <hip/hip_runtime.h>
#include <hip/hip_bf16.h>

// Problem constants
#define BDIM 2
#define LDIM 512
#define CDIM 576
#define HDIM 8
#define CPD  128
#define DK3  24
#define INV_DIV 0.117851130197757920f   // 1/sqrt(72)

// Workspace layout (floats).
static constexpr size_t OFF_Q    = 0;                       // [B,3,H,L,24] 589824
static constexpr size_t OFF_K    = 589824;
static constexpr size_t OFF_V    = 1179648;
static constexpr size_t OFF_G    = 1769472;
static constexpr size_t OFF_BIAS = 2359296;                 // [B,H,L,L] 4194304 ; reused as gq after k_qkmat
static constexpr size_t OFF_ORI  = OFF_BIAS + 4194304;      // [B,3,H,L,L] 12582912
static constexpr size_t OFF_QK   = OFF_ORI + 12582912;      // [B,3,H,L,L] 12582912 ; first 589824 aliased as xn before k_conv
static constexpr size_t OFF_H    = OFF_QK + 12582912;       // [B*L,576]   589824
static constexpr size_t OFF_WPH  = OFF_H + 589824;          // [8][128] = 1024
static constexpr size_t OFF_CS   = OFF_WPH + 1024;          // [16]
static constexpr size_t OFF_XN   = OFF_QK;                  // alias: xn dead before k_conv writes qk

__device__ __forceinline__ float gelu_exact(float v) {
    return 0.5f * v * (1.f + erff(v * 0.70710678118654752f));
}

// ---------------------------------------------------------------------------
// K0: prep for pairbias.
// ---------------------------------------------------------------------------
__global__ __launch_bounds__(256) void k_prep(
    const float* __restrict__ ln2w, const float* __restrict__ ln2b,
    const float* __restrict__ Wp, const float* __restrict__ bp,
    float* __restrict__ wph, float* __restrict__ csum)
{
    const int tid = threadIdx.x;
    for (int i = tid; i < 1024; i += 256) {
        int h = i >> 7, d = i & 127;
        wph[i] = ln2w[d] * Wp[d * 8 + h];
    }
    __syncthreads();
    if (tid < 16) {
        int h = tid & 7;
        float s = 0.f;
        if (tid < 8) {
            for (int d = 0; d < 128; ++d) s += wph[h * 128 + d];
            csum[h] = s;
        } else {
            for (int d = 0; d < 128; ++d) s += ln2b[d] * Wp[d * 8 + h];
            csum[8 + h] = s + bp[h];
        }
    }
}

// ---------------------------------------------------------------------------
// K1a: LN(x) -> xn[1024][576] global.  grid=256, wave per row.
// ---------------------------------------------------------------------------
__global__ __launch_bounds__(256) void k_ln(
    const float* __restrict__ x, const float* __restrict__ ln1w, const float* __restrict__ ln1b,
    float* __restrict__ xn)
{
    const int tid = threadIdx.x;
    const int wid = tid >> 6, lane = tid & 63;
    const int row = blockIdx.x * 4 + wid;
    const float* xr = x + (size_t)row * CDIM;
    float vals[9]; float s = 0.f, sq = 0.f;
#pragma unroll
    for (int u = 0; u < 9; ++u) {
        float v = xr[lane + 64 * u];
        vals[u] = v; s += v; sq += v * v;
    }
#pragma unroll
    for (int o = 32; o; o >>= 1) { s += __shfl_xor(s, o); sq += __shfl_xor(sq, o); }
    float m = s * (1.f / 576.f);
    float inv = rsqrtf(sq * (1.f / 576.f) - m * m + 1e-6f);
    float* xo = xn + (size_t)row * CDIM;
#pragma unroll
    for (int u = 0; u < 9; ++u) {
        int idx = lane + 64 * u;
        xo[idx] = (vals[u] - m) * inv * ln1w[idx] + ln1b[idx];
    }
}

// ---------------------------------------------------------------------------
// K1b: projection GEMM.  block = (mat, grp, rowblk of 64): C[64,192] =
// xn[64 rows, 192 k-slice] @ W[192,192] + b.  A staged k-major (b128 reads),
// W staged in 32-k chunks.  thread = 4 rows x 12 cols.  grid = 4*3*16 = 192.
// ---------------------------------------------------------------------------
__global__ __launch_bounds__(256) void k_proj(
    const float* __restrict__ xn,
    const float* __restrict__ Wq, const float* __restrict__ bq,
    const float* __restrict__ Wk, const float* __restrict__ bk,
    const float* __restrict__ Wv, const float* __restrict__ bv,
    const float* __restrict__ Wg, const float* __restrict__ bg,
    float* __restrict__ qo, float* __restrict__ ko, float* __restrict__ vo, float* __restrict__ go)
{
    __shared__ float As[192 * 64];   // [k][row]
    __shared__ float Bs[32 * 192];   // [k2][col]
    const int tid = threadIdx.x;
    const int bx = blockIdx.x;
    const int mi = bx / 48, rem = bx % 48;
    const int g = rem >> 4, rb = rem & 15;
    const int row0 = rb * 64;

    const float* W  = mi == 0 ? Wq : mi == 1 ? Wk : mi == 2 ? Wv : Wg;
    const float* bb = mi == 0 ? bq : mi == 1 ? bk : mi == 2 ? bv : bg;
    float* op       = mi == 0 ? qo : mi == 1 ? ko : mi == 2 ? vo : go;

    {   // stage As transposed: As[k][r] = xn[row0+r][g*192+k]
        const int r = tid & 63, k4b = tid >> 6;
#pragma unroll
        for (int it = 0; it < 12; ++it) {
            int k4 = k4b + it * 4;
            float4 v = *(const float4*)&xn[(size_t)(row0 + r) * 576 + g * 192 + k4 * 4];
            As[(k4 * 4 + 0) * 64 + r] = v.x;
            As[(k4 * 4 + 1) * 64 + r] = v.y;
            As[(k4 * 4 + 2) * 64 + r] = v.z;
            As[(k4 * 4 + 3) * 64 + r] = v.w;
        }
    }

    const int rg = tid >> 4, cg = tid & 15;
    const int r0 = rg * 4, c0 = cg * 12;
    float acc[4][12] = {};

    for (int kk = 0; kk < 192; kk += 32) {
        __syncthreads();
#pragma unroll
        for (int i = 0; i < 6; ++i) {
            int f = tid + 256 * i;          // 0..1535
            int k2 = f / 48, c4 = f % 48;
            *(float4*)&Bs[k2 * 192 + c4 * 4] = *(const float4*)&W[(size_t)(kk + k2) * 192 + c4 * 4];
        }
        __syncthreads();
#pragma unroll
        for (int k2 = 0; k2 < 32; ++k2) {
            const float4 a  = *(const float4*)&As[(kk + k2) * 64 + r0];
            const float4 b0 = *(const float4*)&Bs[k2 * 192 + c0];
            const float4 b1 = *(const float4*)&Bs[k2 * 192 + c0 + 4];
            const float4 b2 = *(const float4*)&Bs[k2 * 192 + c0 + 8];
            const float ar[4] = {a.x, a.y, a.z, a.w};
#pragma unroll
            for (int r = 0; r < 4; ++r) {
                acc[r][0] = fmaf(ar[r], b0.x, acc[r][0]);
                acc[r][1] = fmaf(ar[r], b0.y, acc[r][1]);
                acc[r][2] = fmaf(ar[r], b0.z, acc[r][2]);
                acc[r][3] = fmaf(ar[r], b0.w, acc[r][3]);
                acc[r][4] = fmaf(ar[r], b1.x, acc[r][4]);
                acc[r][5] = fmaf(ar[r], b1.y, acc[r][5]);
                acc[r][6] = fmaf(ar[r], b1.z, acc[r][6]);
                acc[r][7] = fmaf(ar[r], b1.w, acc[r][7]);
                acc[r][8] = fmaf(ar[r], b2.x, acc[r][8]);
                acc[r][9] = fmaf(ar[r], b2.y, acc[r][9]);
                acc[r][10] = fmaf(ar[r], b2.z, acc[r][10]);
                acc[r][11] = fmaf(ar[r], b2.w, acc[r][11]);
            }
        }
    }

    // write: cols c0..c0+11 lie in ONE head: h = cg/2, d24 = (cg&1)*12
    const int h = cg >> 1, d24 = (cg & 1) * 12;
    const float4 bj0 = *(const float4*)&bb[c0];
    const float4 bj1 = *(const float4*)&bb[c0 + 4];
    const float4 bj2 = *(const float4*)&bb[c0 + 8];
#pragma unroll
    for (int r = 0; r < 4; ++r) {
        int row = row0 + r0 + r;
        int b = row >> 9, l = row & 511;
        float* o = op + ((((size_t)b * 3 + g) * HDIM + h) * LDIM + l) * DK3 + d24;
        *(float4*)(o + 0) = make_float4(acc[r][0] + bj0.x, acc[r][1] + bj0.y,
                                        acc[r][2] + bj0.z, acc[r][3] + bj0.w);
        *(float4*)(o + 4) = make_float4(acc[r][4] + bj1.x, acc[r][5] + bj1.y,
                                        acc[r][6] + bj1.z, acc[r][7] + bj1.w);
        *(float4*)(o + 8) = make_float4(acc[r][8] + bj2.x, acc[r][9] + bj2.y,
                                        acc[r][10] + bj2.z, acc[r][11] + bj2.w);
    }
}

// ---------------------------------------------------------------------------
// K2: pairBias.  ONE THREAD = ONE (b,i,j) ROW.  LN folded analytically.
// grid=2048 x 256 threads.
// ---------------------------------------------------------------------------
__global__ __launch_bounds__(256) void k_pairbias(
    const float* __restrict__ pairX, const float* __restrict__ wph,
    const float* __restrict__ csum, float* __restrict__ bias)
{
    const int row = blockIdx.x * 256 + threadIdx.x;
    const float* rp = pairX + (size_t)row * CPD;

    float acc[8] = {};
    float sum = 0.f, sumsq = 0.f;
    for (int s = 0; s < 8; ++s) {
        float rr[16];
        *(float4*)&rr[0]  = *(const float4*)(rp + s * 16 + 0);
        *(float4*)&rr[4]  = *(const float4*)(rp + s * 16 + 4);
        *(float4*)&rr[8]  = *(const float4*)(rp + s * 16 + 8);
        *(float4*)&rr[12] = *(const float4*)(rp + s * 16 + 12);
#pragma unroll
        for (int k = 0; k < 16; ++k) { sum += rr[k]; sumsq = fmaf(rr[k], rr[k], sumsq); }
        const float* wp_s = wph + s * 16;
#pragma unroll
        for (int h = 0; h < 8; ++h) {
            const float* w = wp_s + h * 128;   // uniform address -> s_load
#pragma unroll
            for (int k = 0; k < 16; ++k) acc[h] = fmaf(rr[k], w[k], acc[h]);
        }
    }
    const float m = sum * (1.f / 128.f);
    const float inv = rsqrtf(sumsq * (1.f / 128.f) - m * m + 1e-6f);
    const int b = row >> 18;
    const int ij = row & 262143;
    float* bo = bias + ((size_t)b << 21) + ij;
#pragma unroll
    for (int h = 0; h < 8; ++h) {
        float o = inv * (acc[h] - m * csum[h]) + csum[8 + h];
        bo[(size_t)h << 18] = o;
    }
}

// ---------------------------------------------------------------------------
// K3: oriQK = q.k^T (K=24) + bias.  stride 28 (16B-aligned rows), d-loop
// vectorized by 4 (b128 LDS reads).  grid=768.
// ---------------------------------------------------------------------------
__global__ __launch_bounds__(256) void k_qkmat(
    const float* __restrict__ q, const float* __restrict__ k,
    const float* __restrict__ bias, float* __restrict__ oriQK)
{
    __shared__ float Kl[512 * 28];   // 57.3 KB
    __shared__ float Ql[32 * 28];
    const int tid = threadIdx.x;
    const int bch = blockIdx.x >> 4;       // b*24 + c*8 + h
    const int itile = blockIdx.x & 15;
    const float* kp = k + (size_t)bch * 512 * 24;
    const float* qp = q + (size_t)bch * 512 * 24 + (size_t)itile * 32 * 24;
    for (int idx = tid; idx < 512 * 24; idx += 256) {
        int j = idx / 24, d = idx - j * 24;
        Kl[j * 28 + d] = kp[idx];
    }
    for (int idx = tid; idx < 32 * 24; idx += 256) {
        int i = idx / 24, d = idx - i * 24;
        Ql[i * 28 + d] = qp[idx];
    }
    __syncthreads();

    const int ti = tid >> 4, tj = tid & 15;
    const int b = bch / 24, h = bch & 7;
    const float* biasp = bias + ((size_t)(b * 8 + h) * 512 + itile * 32) * 512;
    float* outp = oriQK + (size_t)bch * 262144 + (size_t)itile * 32 * 512;

    for (int cc = 0; cc < 4; ++cc) {
        float acc[2][8] = {};
#pragma unroll
        for (int d4 = 0; d4 < 6; ++d4) {
            const float4 q0 = *(const float4*)&Ql[(ti * 2 + 0) * 28 + d4 * 4];
            const float4 q1 = *(const float4*)&Ql[(ti * 2 + 1) * 28 + d4 * 4];
#pragma unroll
            for (int u = 0; u < 8; ++u) {
                const float4 kv = *(const float4*)&Kl[(cc * 128 + u * 16 + tj) * 28 + d4 * 4];
                acc[0][u] = fmaf(q0.x, kv.x, fmaf(q0.y, kv.y, fmaf(q0.z, kv.z, fmaf(q0.w, kv.w, acc[0][u]))));
                acc[1][u] = fmaf(q1.x, kv.x, fmaf(q1.y, kv.y, fmaf(q1.z, kv.z, fmaf(q1.w, kv.w, acc[1][u]))));
            }
        }
#pragma unroll
        for (int r = 0; r < 2; ++r) {
            int i = ti * 2 + r;
#pragma unroll
            for (int u = 0; u < 8; ++u) {
                int j = cc * 128 + u * 16 + tj;
                outp[(size_t)i * 512 + j] = acc[r][u] + biasp[(size_t)i * 512 + j];
            }
        }
    }
}

// ---------------------------------------------------------------------------
// K4: 5x5 conv + fused qk/gq epilogue.  grid=512, 2 blocks/CU.
// v3: weights read DIRECTLY from global with wave-uniform indices
// (scalar/broadcast loads, L1-resident) -- removes the 1200-b128/wave DS
// storm that made v2 LDS-unit-bound.  Tile staging unchanged.
// ---------------------------------------------------------------------------
__global__ __launch_bounds__(256, 2) void k_conv(
    const float* __restrict__ oriQK, const float* __restrict__ convW, const float* __restrict__ convB,
    float* __restrict__ qk, float* __restrict__ gq)
{
    __shared__ float tile[8 * 36 * 40];   // 46080 B, per-branch
    const int tid = threadIdx.x;
    const int bx = blockIdx.x;
    const int b = bx >> 8, rem = bx & 255;
    const int i0 = (rem >> 4) * 32, j0 = (rem & 15) * 32;

    const int jg = tid & 7, ii = tid >> 3;   // 8 col-groups x 32 rows
    const int j4 = jg * 4;
    float acc[8][4] = {};                    // [h_out][jcol]

    for (int c = 0; c < 3; ++c) {
        __syncthreads();   // protect previous iteration's reads
        // stage 8 channels of the 36x36 halo tile
        for (int idx = tid; idx < 8 * 1296; idx += 256) {
            int ch = idx / 1296;
            int r = idx - ch * 1296;
            int iw = r / 36, jw = r - iw * 36;
            int gi = i0 - 2 + iw, gj = j0 - 2 + jw;
            float v = 0.f;
            if ((unsigned)gi < 512u && (unsigned)gj < 512u)
                v = oriQK[((size_t)(b * 24 + c * 8 + ch) << 18) + ((size_t)gi << 9) + gj];
            tile[ch * 1440 + iw * 40 + jw] = v;
        }
        __syncthreads();

        const float* wb = convW + c * 1600;   // [h_out*200 + hi*25 + kh*5 + kw]
        for (int hi = 0; hi < 8; ++hi) {
            const float* tch = &tile[hi * 1440];
#pragma unroll
            for (int kh = 0; kh < 5; ++kh) {
                const float* trow = &tch[(ii + kh) * 40 + j4];
                float v[8];
                *(float4*)&v[0] = *(const float4*)&trow[0];
                *(float4*)&v[4] = *(const float4*)&trow[4];
#pragma unroll
                for (int kw = 0; kw < 5; ++kw) {
                    const float* wt = wb + hi * 25 + kh * 5 + kw;   // uniform
                    const float w0 = wt[0],    w1 = wt[200],  w2 = wt[400],  w3 = wt[600];
                    const float w4 = wt[800],  w5 = wt[1000], w6 = wt[1200], w7 = wt[1400];
#pragma unroll
                    for (int j = 0; j < 4; ++j) {
                        float vv = v[kw + j];
                        acc[0][j] = fmaf(w0, vv, acc[0][j]);
                        acc[1][j] = fmaf(w1, vv, acc[1][j]);
                        acc[2][j] = fmaf(w2, vv, acc[2][j]);
                        acc[3][j] = fmaf(w3, vv, acc[3][j]);
                        acc[4][j] = fmaf(w4, vv, acc[4][j]);
                        acc[5][j] = fmaf(w5, vv, acc[5][j]);
                        acc[6][j] = fmaf(w6, vv, acc[6][j]);
                        acc[7][j] = fmaf(w7, vv, acc[7][j]);
                    }
                }
            }
        }
    }

    // epilogue: centers re-read from global (L2-hot), write qk and gq
    const int gi = i0 + ii, gj = j0 + j4;
    const float* orib = oriQK + ((size_t)(b * 24) << 18) + ((size_t)gi << 9) + gj;
    float* qkb = qk + ((size_t)(b * 24) << 18) + ((size_t)gi << 9) + gj;
    float gqv[4][8];
#pragma unroll
    for (int h = 0; h < 8; ++h) {
        float cv = convB[h] + convB[8 + h] + convB[16 + h];   // uniform
        float c0 = acc[h][0] + cv, c1 = acc[h][1] + cv, c2 = acc[h][2] + cv, c3 = acc[h][3] + cv;
        float m0 = 0, m1 = 0, m2 = 0, m3 = 0;
#pragma unroll
        for (int c = 0; c < 3; ++c) {
            const float4 t = *(const float4*)(orib + ((size_t)(c * 8 + h) << 18));
            m0 += t.x; m1 += t.y; m2 += t.z; m3 += t.w;
            float4 o = make_float4((t.x + c0) * INV_DIV, (t.y + c1) * INV_DIV,
                                   (t.z + c2) * INV_DIV, (t.w + c3) * INV_DIV);
            *(float4*)(qkb + ((size_t)(c * 8 + h) << 18)) = o;
        }
        gqv[0][h] = gelu_exact((m0 * (1.f / 3.f) + c0) * INV_DIV);
        gqv[1][h] = gelu_exact((m1 * (1.f / 3.f) + c1) * INV_DIV);
        gqv[2][h] = gelu_exact((m2 * (1.f / 3.f) + c2) * INV_DIV);
        gqv[3][h] = gelu_exact((m3 * (1.f / 3.f) + c3) * INV_DIV);
    }
    float* gqb = gq + (((size_t)(b * 512 + gi) << 9) + gj) * 8;
#pragma unroll
    for (int jc = 0; jc < 4; ++jc) {
        *(float4*)(gqb + jc * 8)     = make_float4(gqv[jc][0], gqv[jc][1], gqv[jc][2], gqv[jc][3]);
        *(float4*)(gqb + jc * 8 + 4) = make_float4(gqv[jc][4], gqv[jc][5], gqv[jc][6], gqv[jc][7]);
    }
}

// ---------------------------------------------------------------------------
// K5: out2 = gq(8) @ Wpr(8x128) + bpr.  grid=2048, 256 pos/block.
// ---------------------------------------------------------------------------
__global__ __launch_bounds__(256) void k_out2(
    const float* __restrict__ gq, const float* __restrict__ Wpr, const float* __restrict__ bpr,
    float* __restrict__ out2)
{
    __shared__ float WprS[8 * 128];
    __shared__ float bprS[128];
    const int tid = threadIdx.x;
    for (int i = tid; i < 1024; i += 256) WprS[i] = Wpr[i];
    if (tid < 128) bprS[tid] = bpr[tid];
    __syncthreads();

    const int p = (tid & 31) * 4;
    float4 wv[8];
#pragma unroll
    for (int h = 0; h < 8; ++h) wv[h] = *(const float4*)&WprS[h * 128 + p];
    const float4 bv = *(const float4*)&bprS[p];

    size_t pos0 = (size_t)blockIdx.x * 256 + (tid >> 5);
    for (int it = 0; it < 32; ++it) {
        size_t pos = pos0 + it * 8;
        const float4 ga = *(const float4*)(gq + pos * 8);
        const float4 gb = *(const float4*)(gq + pos * 8 + 4);
        float4 o = bv;
        o.x += ga.x * wv[0].x + ga.y * wv[1].x + ga.z * wv[2].x + ga.w * wv[3].x
             + gb.x * wv[4].x + gb.y * wv[5].x + gb.z * wv[6].x + gb.w * wv[7].x;
        o.y += ga.x * wv[0].y + ga.y * wv[1].y + ga.z * wv[2].y + ga.w * wv[3].y
             + gb.x * wv[4].y + gb.y * wv[5].y + gb.z * wv[6].y + gb.w * wv[7].y;
        o.z += ga.x * wv[0].z + ga.y * wv[1].z + ga.z * wv[2].z + ga.w * wv[3].z
             + gb.x * wv[4].z + gb.y * wv[5].z + gb.z * wv[6].z + gb.w * wv[7].z;
        o.w += ga.x * wv[0].w + ga.y * wv[1].w + ga.z * wv[2].w + ga.w * wv[3].w
             + gb.x * wv[4].w + gb.y * wv[5].w + gb.z * wv[6].w + gb.w * wv[7].w;
        *(float4*)(out2 + pos * 128 + p) = o;
    }
}

// ---------------------------------------------------------------------------
// K6: softmax over qk rows + P@V + sigmoid(gate).  wave per row, V in LDS
// (stride 28).  grid=768.
// ---------------------------------------------------------------------------
__global__ __launch_bounds__(256) void k_softmax_pv(
    const float* __restrict__ qk, const float* __restrict__ v, const float* __restrict__ gate,
    float* __restrict__ houts)
{
    __shared__ float Vl[512 * 28];   // 57.3 KB
    const int tid = threadIdx.x;
    const int bch = blockIdx.x >> 4, itile = blockIdx.x & 15;
    const float* vp = v + (size_t)bch * (512 * 24);
    for (int idx = tid; idx < 512 * 24; idx += 256) {
        int j = idx / 24, d = idx - j * 24;
        Vl[j * 28 + d] = vp[idx];
    }
    __syncthreads();

    const int wid = tid >> 6, lane = tid & 63;
    const int b = bch / 24, c = (bch % 24) >> 3, h = bch & 7;
    for (int rr = 0; rr < 8; ++rr) {
        const int i = itile * 32 + wid * 8 + rr;
        const float* row = qk + ((size_t)bch * 512 + i) * 512;
        float e[8]; float mx = -1e30f;
#pragma unroll
        for (int u = 0; u < 8; ++u) { e[u] = row[lane + 64 * u]; mx = fmaxf(mx, e[u]); }
#pragma unroll
        for (int o = 32; o; o >>= 1) mx = fmaxf(mx, __shfl_xor(mx, o));
        float s = 0.f;
#pragma unroll
        for (int u = 0; u < 8; ++u) { e[u] = __expf(e[u] - mx); s += e[u]; }
#pragma unroll
        for (int o = 32; o; o >>= 1) s += __shfl_xor(s, o);
        float inv = 1.f / s;

        float4 a4[6] = {};
#pragma unroll
        for (int u = 0; u < 8; ++u) {
            float p = e[u] * inv;
            const float* vr = &Vl[(u * 64 + lane) * 28];
#pragma unroll
            for (int k = 0; k < 6; ++k) {
                float4 vv = *(const float4*)(vr + 4 * k);
                a4[k].x = fmaf(p, vv.x, a4[k].x);
                a4[k].y = fmaf(p, vv.y, a4[k].y);
                a4[k].z = fmaf(p, vv.z, a4[k].z);
                a4[k].w = fmaf(p, vv.w, a4[k].w);
            }
        }
#pragma unroll
        for (int o = 32; o; o >>= 1) {
#pragma unroll
            for (int k = 0; k < 6; ++k) {
                a4[k].x += __shfl_xor(a4[k].x, o);
                a4[k].y += __shfl_xor(a4[k].y, o);
                a4[k].z += __shfl_xor(a4[k].z, o);
                a4[k].w += __shfl_xor(a4[k].w, o);
            }
        }
        const float* gp = gate + ((size_t)bch * 512 + i) * 24;
        float* op = houts + ((size_t)(b * 512 + i)) * 576 + c * 192 + h * 24;
#pragma unroll
        for (int k = 0; k < 6; ++k) {
            float4 g4 = *(const float4*)(gp + 4 * k);
            float4 o4;
            o4.x = a4[k].x / (1.f + __expf(-g4.x));
            o4.y = a4[k].y / (1.f + __expf(-g4.y));
            o4.z = a4[k].z / (1.f + __expf(-g4.z));
            o4.w = a4[k].w / (1.f + __expf(-g4.w));
            if (lane == 0) *(float4*)(op + 4 * k) = o4;
        }
    }
}

// ---------------------------------------------------------------------------
// K7: out1 = houts @ Wo + bo + x*g.  Tiled GEMM: 32x64 tile, BK=32, grid=288.
// ---------------------------------------------------------------------------
__global__ __launch_bounds__(256) void k_out1(
    const float* __restrict__ houts, const float* __restrict__ Wo, const float* __restrict__ bo,
    const float* __restrict__ x, const float* __restrict__ gsc,
    float* __restrict__ out1)
{
    __shared__ float As[32 * 33];
    __shared__ float Bs[32 * 64];
    const int tid = threadIdx.x;
    const int mt = blockIdx.x / 9, nt = blockIdx.x % 9;
    const int m0 = mt * 32, n0 = nt * 64;
    const int tn = tid & 15, tm = tid >> 4;
    float acc[2][4] = {};

    for (int kk = 0; kk < 576; kk += 32) {
        {
            int idx = tid;
#pragma unroll
            for (int i = 0; i < 4; ++i, idx += 256) {
                int k2 = idx & 31, m = idx >> 5;
                As[m * 33 + k2] = houts[(size_t)(m0 + m) * 576 + kk + k2];
            }
        }
        {
            int idx = tid;
#pragma unroll
            for (int i = 0; i < 8; ++i, idx += 256) {
                int n = idx & 63, k2 = idx >> 6;
                Bs[k2 * 64 + n] = Wo[(size_t)(kk + k2) * 576 + n0 + n];
            }
        }
        __syncthreads();
#pragma unroll
        for (int k2 = 0; k2 < 32; ++k2) {
            float a0 = As[(tm * 2 + 0) * 33 + k2];
            float a1 = As[(tm * 2 + 1) * 33 + k2];
            const float4 bv = *(const float4*)&Bs[k2 * 64 + tn * 4];
            acc[0][0] += a0 * bv.x; acc[0][1] += a0 * bv.y; acc[0][2] += a0 * bv.z; acc[0][3] += a0 * bv.w;
            acc[1][0] += a1 * bv.x; acc[1][1] += a1 * bv.y; acc[1][2] += a1 * bv.z; acc[1][3] += a1 * bv.w;
        }
        __syncthreads();
    }

    const float gv = gsc[0];
    const float4 b4 = *(const float4*)&bo[n0 + tn * 4];
#pragma unroll
    for (int r = 0; r < 2; ++r) {
        size_t row = (size_t)m0 + tm * 2 + r;
        size_t off = row * 576 + n0 + tn * 4;
        const float4 x4 = *(const float4*)&x[off];
        float4 o;
        o.x = acc[r][0] + b4.x + x4.x * gv;
        o.y = acc[r][1] + b4.y + x4.y * gv;
        o.z = acc[r][2] + b4.z + x4.z * gv;
        o.w = acc[r][3] + b4.w + x4.w * gv;
        *(float4*)&out1[off] = o;
    }
}

// ---------------------------------------------------------------------------
extern "C" void kernel_launch(void* const* d_in, const int* in_sizes, int n_in,
                              void* d_out, int out_size, void* d_ws, size_t ws_size,
                              hipStream_t stream) {
    const float* x     = (const float*)d_in[0];
    const float* pairX = (const float*)d_in[1];
    const float* g     = (const float*)d_in[2];
    const float* ln1w  = (const float*)d_in[3];
    const float* ln1b  = (const float*)d_in[4];
    const float* ln2w  = (const float*)d_in[5];
    const float* ln2b  = (const float*)d_in[6];
    const float* Wq    = (const float*)d_in[7];
    const float* bq    = (const float*)d_in[8];
    const float* Wk    = (const float*)d_in[9];
    const float* bk    = (const float*)d_in[10];
    const float* Wv    = (const float*)d_in[11];
    const float* bv    = (const float*)d_in[12];
    const float* Wg    = (const float*)d_in[13];
    const float* bg    = (const float*)d_in[14];
    const float* convW = (const float*)d_in[15];
    const float* convB = (const float*)d_in[16];
    const float* Wp    = (const float*)d_in[17];
    const float* bp    = (const float*)d_in[18];
    const float* Wpr   = (const float*)d_in[19];
    const float* bpr   = (const float*)d_in[20];
    const float* Wo    = (const float*)d_in[21];
    const float* bo    = (const float*)d_in[22];

    float* ws   = (float*)d_ws;
    float* q    = ws + OFF_Q;
    float* k    = ws + OFF_K;
    float* vv   = ws + OFF_V;
    float* gt   = ws + OFF_G;
    float* bias = ws + OFF_BIAS;
    float* gq   = ws + OFF_BIAS;   // alias: bias dead after k_qkmat
    float* ori  = ws + OFF_ORI;
    float* qkb  = ws + OFF_QK;
    float* xn   = ws + OFF_XN;     // alias onto qk region (dead until k_conv)
    float* hout = ws + OFF_H;
    float* wph  = ws + OFF_WPH;
    float* csum = ws + OFF_CS;

    float* out1 = (float*)d_out;
    float* out2 = out1 + 589824;

    k_prep<<<dim3(1), dim3(256), 0, stream>>>(ln2w, ln2b, Wp, bp, wph, csum);
    k_ln<<<dim3(256), dim3(256), 0, stream>>>(x, ln1w, ln1b, xn);
    k_proj<<<dim3(192), dim3(256), 0, stream>>>(xn, Wq, bq, Wk, bk, Wv, bv, Wg, bg,
                                                q, k, vv, gt);
    k_pairbias<<<dim3(2048), dim3(256), 0, stream>>>(pairX, wph, csum, bias);
    k_qkmat<<<dim3(768), dim3(256), 0, stream>>>(q, k, bias, ori);
    k_conv<<<dim3(512), dim3(256), 0, stream>>>(ori, convW, convB, qkb, gq);
    k_out2<<<dim3(2048), dim3(256), 0, stream>>>(gq, Wpr, bpr, out2);
    k_softmax_pv<<<dim3(768), dim3(256), 0, stream>>>(qkb, vv, gt, hout);
    k_out1<<<dim3(288), dim3(256), 0, stream>>>(hout, Wo, bo, x, g, out1);
}

// Round 7
// 460.823 us; speedup vs baseline: 2.3087x; 1.1711x over previous
//
#include <hip/hip_runtime.h>
#include <hip/hip_bf16.h>

// Problem constants
#define BDIM 2
#define LDIM 512
#define CDIM 576
#define HDIM 8
#define CPD  128
#define DK3  24
#define INV_DIV 0.117851130197757920f   // 1/sqrt(72)

// Workspace layout (floats).
static constexpr size_t OFF_Q    = 0;                       // [B,3,H,L,24] 589824
static constexpr size_t OFF_K    = 589824;
static constexpr size_t OFF_V    = 1179648;
static constexpr size_t OFF_G    = 1769472;
static constexpr size_t OFF_BIAS = 2359296;                 // [B,H,L,L] 4194304
static constexpr size_t OFF_ORI  = OFF_BIAS + 4194304;      // [B,3,H,L,L] 12582912
static constexpr size_t OFF_QK   = OFF_ORI + 12582912;      // [B,3,H,L,L] 12582912 ; first 589824 aliased as xn before k_conv
static constexpr size_t OFF_H    = OFF_QK + 12582912;       // [B*L,576]   589824
static constexpr size_t OFF_WPH  = OFF_H + 589824;          // [8][128] = 1024
static constexpr size_t OFF_CS   = OFF_WPH + 1024;          // [16]
static constexpr size_t OFF_XN   = OFF_QK;                  // alias: xn dead before k_conv writes qk

__device__ __forceinline__ float gelu_exact(float v) {
    return 0.5f * v * (1.f + erff(v * 0.70710678118654752f));
}

// ---------------------------------------------------------------------------
// K0: prep for pairbias (parallelized: 256 threads, shfl reduce).
// ---------------------------------------------------------------------------
__global__ __launch_bounds__(256) void k_prep(
    const float* __restrict__ ln2w, const float* __restrict__ ln2b,
    const float* __restrict__ Wp, const float* __restrict__ bp,
    float* __restrict__ wph, float* __restrict__ csum)
{
    __shared__ float wl[1024];
    const int tid = threadIdx.x;
    for (int i = tid; i < 1024; i += 256) {
        int h = i >> 7, d = i & 127;
        float v = ln2w[d] * Wp[d * 8 + h];
        wl[i] = v; wph[i] = v;
    }
    __syncthreads();
    const int h = tid >> 5, c4 = tid & 31;
    float p = wl[h * 128 + c4 * 4] + wl[h * 128 + c4 * 4 + 1]
            + wl[h * 128 + c4 * 4 + 2] + wl[h * 128 + c4 * 4 + 3];
#pragma unroll
    for (int o = 1; o < 32; o <<= 1) p += __shfl_xor(p, o);
    if (c4 == 0) csum[h] = p;
    float q = 0.f;
#pragma unroll
    for (int k = 0; k < 4; ++k) { int d = c4 * 4 + k; q = fmaf(ln2b[d], Wp[d * 8 + h], q); }
#pragma unroll
    for (int o = 1; o < 32; o <<= 1) q += __shfl_xor(q, o);
    if (c4 == 0) csum[8 + h] = q + bp[h];
}

// ---------------------------------------------------------------------------
// K1a: LN(x) -> xn[1024][576] global.  grid=256, wave per row.
// ---------------------------------------------------------------------------
__global__ __launch_bounds__(256) void k_ln(
    const float* __restrict__ x, const float* __restrict__ ln1w, const float* __restrict__ ln1b,
    float* __restrict__ xn)
{
    const int tid = threadIdx.x;
    const int wid = tid >> 6, lane = tid & 63;
    const int row = blockIdx.x * 4 + wid;
    const float* xr = x + (size_t)row * CDIM;
    float vals[9]; float s = 0.f, sq = 0.f;
#pragma unroll
    for (int u = 0; u < 9; ++u) {
        float v = xr[lane + 64 * u];
        vals[u] = v; s += v; sq += v * v;
    }
#pragma unroll
    for (int o = 32; o; o >>= 1) { s += __shfl_xor(s, o); sq += __shfl_xor(sq, o); }
    float m = s * (1.f / 576.f);
    float inv = rsqrtf(sq * (1.f / 576.f) - m * m + 1e-6f);
    float* xo = xn + (size_t)row * CDIM;
#pragma unroll
    for (int u = 0; u < 9; ++u) {
        int idx = lane + 64 * u;
        xo[idx] = (vals[u] - m) * inv * ln1w[idx] + ln1b[idx];
    }
}

// ---------------------------------------------------------------------------
// K1b: projection GEMM.  grid = 4*3*16 = 192.
// ---------------------------------------------------------------------------
__global__ __launch_bounds__(256) void k_proj(
    const float* __restrict__ xn,
    const float* __restrict__ Wq, const float* __restrict__ bq,
    const float* __restrict__ Wk, const float* __restrict__ bk,
    const float* __restrict__ Wv, const float* __restrict__ bv,
    const float* __restrict__ Wg, const float* __restrict__ bg,
    float* __restrict__ qo, float* __restrict__ ko, float* __restrict__ vo, float* __restrict__ go)
{
    __shared__ float As[192 * 64];   // [k][row]
    __shared__ float Bs[32 * 192];   // [k2][col]
    const int tid = threadIdx.x;
    const int bx = blockIdx.x;
    const int mi = bx / 48, rem = bx % 48;
    const int g = rem >> 4, rb = rem & 15;
    const int row0 = rb * 64;

    const float* W  = mi == 0 ? Wq : mi == 1 ? Wk : mi == 2 ? Wv : Wg;
    const float* bb = mi == 0 ? bq : mi == 1 ? bk : mi == 2 ? bv : bg;
    float* op       = mi == 0 ? qo : mi == 1 ? ko : mi == 2 ? vo : go;

    {   // stage As transposed: As[k][r] = xn[row0+r][g*192+k]
        const int r = tid & 63, k4b = tid >> 6;
#pragma unroll
        for (int it = 0; it < 12; ++it) {
            int k4 = k4b + it * 4;
            float4 v = *(const float4*)&xn[(size_t)(row0 + r) * 576 + g * 192 + k4 * 4];
            As[(k4 * 4 + 0) * 64 + r] = v.x;
            As[(k4 * 4 + 1) * 64 + r] = v.y;
            As[(k4 * 4 + 2) * 64 + r] = v.z;
            As[(k4 * 4 + 3) * 64 + r] = v.w;
        }
    }

    const int rg = tid >> 4, cg = tid & 15;
    const int r0 = rg * 4, c0 = cg * 12;
    float acc[4][12] = {};

    for (int kk = 0; kk < 192; kk += 32) {
        __syncthreads();
#pragma unroll
        for (int i = 0; i < 6; ++i) {
            int f = tid + 256 * i;          // 0..1535
            int k2 = f / 48, c4 = f % 48;
            *(float4*)&Bs[k2 * 192 + c4 * 4] = *(const float4*)&W[(size_t)(kk + k2) * 192 + c4 * 4];
        }
        __syncthreads();
#pragma unroll
        for (int k2 = 0; k2 < 32; ++k2) {
            const float4 a  = *(const float4*)&As[(kk + k2) * 64 + r0];
            const float4 b0 = *(const float4*)&Bs[k2 * 192 + c0];
            const float4 b1 = *(const float4*)&Bs[k2 * 192 + c0 + 4];
            const float4 b2 = *(const float4*)&Bs[k2 * 192 + c0 + 8];
            const float ar[4] = {a.x, a.y, a.z, a.w};
#pragma unroll
            for (int r = 0; r < 4; ++r) {
                acc[r][0] = fmaf(ar[r], b0.x, acc[r][0]);
                acc[r][1] = fmaf(ar[r], b0.y, acc[r][1]);
                acc[r][2] = fmaf(ar[r], b0.z, acc[r][2]);
                acc[r][3] = fmaf(ar[r], b0.w, acc[r][3]);
                acc[r][4] = fmaf(ar[r], b1.x, acc[r][4]);
                acc[r][5] = fmaf(ar[r], b1.y, acc[r][5]);
                acc[r][6] = fmaf(ar[r], b1.z, acc[r][6]);
                acc[r][7] = fmaf(ar[r], b1.w, acc[r][7]);
                acc[r][8] = fmaf(ar[r], b2.x, acc[r][8]);
                acc[r][9] = fmaf(ar[r], b2.y, acc[r][9]);
                acc[r][10] = fmaf(ar[r], b2.z, acc[r][10]);
                acc[r][11] = fmaf(ar[r], b2.w, acc[r][11]);
            }
        }
    }

    const int h = cg >> 1, d24 = (cg & 1) * 12;
    const float4 bj0 = *(const float4*)&bb[c0];
    const float4 bj1 = *(const float4*)&bb[c0 + 4];
    const float4 bj2 = *(const float4*)&bb[c0 + 8];
#pragma unroll
    for (int r = 0; r < 4; ++r) {
        int row = row0 + r0 + r;
        int b = row >> 9, l = row & 511;
        float* o = op + ((((size_t)b * 3 + g) * HDIM + h) * LDIM + l) * DK3 + d24;
        *(float4*)(o + 0) = make_float4(acc[r][0] + bj0.x, acc[r][1] + bj0.y,
                                        acc[r][2] + bj0.z, acc[r][3] + bj0.w);
        *(float4*)(o + 4) = make_float4(acc[r][4] + bj1.x, acc[r][5] + bj1.y,
                                        acc[r][6] + bj1.z, acc[r][7] + bj1.w);
        *(float4*)(o + 8) = make_float4(acc[r][8] + bj2.x, acc[r][9] + bj2.y,
                                        acc[r][10] + bj2.z, acc[r][11] + bj2.w);
    }
}

// ---------------------------------------------------------------------------
// K2: pairBias.  ONE THREAD = ONE (b,i,j) ROW.  LN folded analytically.
// ---------------------------------------------------------------------------
__global__ __launch_bounds__(256) void k_pairbias(
    const float* __restrict__ pairX, const float* __restrict__ wph,
    const float* __restrict__ csum, float* __restrict__ bias)
{
    const int row = blockIdx.x * 256 + threadIdx.x;
    const float* rp = pairX + (size_t)row * CPD;

    float acc[8] = {};
    float sum = 0.f, sumsq = 0.f;
    for (int s = 0; s < 8; ++s) {
        float rr[16];
        *(float4*)&rr[0]  = *(const float4*)(rp + s * 16 + 0);
        *(float4*)&rr[4]  = *(const float4*)(rp + s * 16 + 4);
        *(float4*)&rr[8]  = *(const float4*)(rp + s * 16 + 8);
        *(float4*)&rr[12] = *(const float4*)(rp + s * 16 + 12);
#pragma unroll
        for (int k = 0; k < 16; ++k) { sum += rr[k]; sumsq = fmaf(rr[k], rr[k], sumsq); }
        const float* wp_s = wph + s * 16;
#pragma unroll
        for (int h = 0; h < 8; ++h) {
            const float* w = wp_s + h * 128;   // uniform address -> s_load
#pragma unroll
            for (int k = 0; k < 16; ++k) acc[h] = fmaf(rr[k], w[k], acc[h]);
        }
    }
    const float m = sum * (1.f / 128.f);
    const float inv = rsqrtf(sumsq * (1.f / 128.f) - m * m + 1e-6f);
    const int b = row >> 18;
    const int ij = row & 262143;
    float* bo = bias + ((size_t)b << 21) + ij;
#pragma unroll
    for (int h = 0; h < 8; ++h) {
        float o = inv * (acc[h] - m * csum[h]) + csum[8 + h];
        bo[(size_t)h << 18] = o;
    }
}

// ---------------------------------------------------------------------------
// K3: oriQK = q.k^T (K=24) + bias.  grid=768.
// ---------------------------------------------------------------------------
__global__ __launch_bounds__(256) void k_qkmat(
    const float* __restrict__ q, const float* __restrict__ k,
    const float* __restrict__ bias, float* __restrict__ oriQK)
{
    __shared__ float Kl[512 * 28];   // 57.3 KB
    __shared__ float Ql[32 * 28];
    const int tid = threadIdx.x;
    const int bch = blockIdx.x >> 4;       // b*24 + c*8 + h
    const int itile = blockIdx.x & 15;
    const float* kp = k + (size_t)bch * 512 * 24;
    const float* qp = q + (size_t)bch * 512 * 24 + (size_t)itile * 32 * 24;
    for (int idx = tid; idx < 512 * 24; idx += 256) {
        int j = idx / 24, d = idx - j * 24;
        Kl[j * 28 + d] = kp[idx];
    }
    for (int idx = tid; idx < 32 * 24; idx += 256) {
        int i = idx / 24, d = idx - i * 24;
        Ql[i * 28 + d] = qp[idx];
    }
    __syncthreads();

    const int ti = tid >> 4, tj = tid & 15;
    const int b = bch / 24, h = bch & 7;
    const float* biasp = bias + ((size_t)(b * 8 + h) * 512 + itile * 32) * 512;
    float* outp = oriQK + (size_t)bch * 262144 + (size_t)itile * 32 * 512;

    for (int cc = 0; cc < 4; ++cc) {
        float acc[2][8] = {};
#pragma unroll
        for (int d4 = 0; d4 < 6; ++d4) {
            const float4 q0 = *(const float4*)&Ql[(ti * 2 + 0) * 28 + d4 * 4];
            const float4 q1 = *(const float4*)&Ql[(ti * 2 + 1) * 28 + d4 * 4];
#pragma unroll
            for (int u = 0; u < 8; ++u) {
                const float4 kv = *(const float4*)&Kl[(cc * 128 + u * 16 + tj) * 28 + d4 * 4];
                acc[0][u] = fmaf(q0.x, kv.x, fmaf(q0.y, kv.y, fmaf(q0.z, kv.z, fmaf(q0.w, kv.w, acc[0][u]))));
                acc[1][u] = fmaf(q1.x, kv.x, fmaf(q1.y, kv.y, fmaf(q1.z, kv.z, fmaf(q1.w, kv.w, acc[1][u]))));
            }
        }
#pragma unroll
        for (int r = 0; r < 2; ++r) {
            int i = ti * 2 + r;
#pragma unroll
            for (int u = 0; u < 8; ++u) {
                int j = cc * 128 + u * 16 + tj;
                outp[(size_t)i * 512 + j] = acc[r][u] + biasp[(size_t)i * 512 + j];
            }
        }
    }
}

// ---------------------------------------------------------------------------
// K4: 5x5 conv + fused qk epilogue + FUSED out2 (gelu-mean GEMV + 268MB write).
// grid=512, 2 blocks/CU (tile 46KB + gq_lds 32KB = 78.8KB).
// Centers kept in registers (cen[3][8][4]) -- no global re-read.
// ---------------------------------------------------------------------------
__global__ __launch_bounds__(256, 2) void k_conv(
    const float* __restrict__ oriQK, const float* __restrict__ convW, const float* __restrict__ convB,
    const float* __restrict__ Wpr, const float* __restrict__ bpr,
    float* __restrict__ qk, float* __restrict__ out2)
{
    __shared__ float tile[8 * 36 * 40];   // 46080 B
    __shared__ float gql[8 * 1024];       // 32768 B  [h][pos], broadcast reads
    const int tid = threadIdx.x;
    const int bx = blockIdx.x;
    const int b = bx >> 8, rem = bx & 255;
    const int i0 = (rem >> 4) * 32, j0 = (rem & 15) * 32;

    const int jg = tid & 7, ii = tid >> 3;   // 8 col-groups x 32 rows
    const int j4 = jg * 4;
    float acc[8][4] = {};                    // [h_out][jcol]
    float cen[3][8][4];                      // branch centers

    for (int c = 0; c < 3; ++c) {
        __syncthreads();   // protect previous iteration's reads
        for (int idx = tid; idx < 8 * 1296; idx += 256) {
            int ch = idx / 1296;
            int r = idx - ch * 1296;
            int iw = r / 36, jw = r - iw * 36;
            int gi = i0 - 2 + iw, gj = j0 - 2 + jw;
            float v = 0.f;
            if ((unsigned)gi < 512u && (unsigned)gj < 512u)
                v = oriQK[((size_t)(b * 24 + c * 8 + ch) << 18) + ((size_t)gi << 9) + gj];
            tile[ch * 1440 + iw * 40 + jw] = v;
        }
        __syncthreads();

        const float* wb = convW + c * 1600;   // uniform indices -> s_loads
        for (int hi = 0; hi < 8; ++hi) {
            const float* tch = &tile[hi * 1440];
#pragma unroll
            for (int kh = 0; kh < 5; ++kh) {
                const float* trow = &tch[(ii + kh) * 40 + j4];
                float v[8];
                *(float4*)&v[0] = *(const float4*)&trow[0];
                *(float4*)&v[4] = *(const float4*)&trow[4];
#pragma unroll
                for (int kw = 0; kw < 5; ++kw) {
                    const float* wt = wb + hi * 25 + kh * 5 + kw;
                    const float w0 = wt[0],    w1 = wt[200],  w2 = wt[400],  w3 = wt[600];
                    const float w4 = wt[800],  w5 = wt[1000], w6 = wt[1200], w7 = wt[1400];
#pragma unroll
                    for (int j = 0; j < 4; ++j) {
                        float vv = v[kw + j];
                        acc[0][j] = fmaf(w0, vv, acc[0][j]);
                        acc[1][j] = fmaf(w1, vv, acc[1][j]);
                        acc[2][j] = fmaf(w2, vv, acc[2][j]);
                        acc[3][j] = fmaf(w3, vv, acc[3][j]);
                        acc[4][j] = fmaf(w4, vv, acc[4][j]);
                        acc[5][j] = fmaf(w5, vv, acc[5][j]);
                        acc[6][j] = fmaf(w6, vv, acc[6][j]);
                        acc[7][j] = fmaf(w7, vv, acc[7][j]);
                    }
                }
            }
        }
        // capture this branch's centers while the tile is live
#pragma unroll
        for (int h = 0; h < 8; ++h) {
            const float* tr = &tile[h * 1440 + (ii + 2) * 40 + j4 + 2];
            cen[c][h][0] = tr[0]; cen[c][h][1] = tr[1];
            cen[c][h][2] = tr[2]; cen[c][h][3] = tr[3];
        }
    }

    // epilogue 1: qk writes + gelu(mean) into gq_lds
    const int gi = i0 + ii, gj = j0 + j4;
    float* qkb = qk + ((size_t)(b * 24) << 18) + ((size_t)gi << 9) + gj;
#pragma unroll
    for (int h = 0; h < 8; ++h) {
        float cv = convB[h] + convB[8 + h] + convB[16 + h];   // uniform
        float cj[4];
#pragma unroll
        for (int j = 0; j < 4; ++j) cj[j] = acc[h][j] + cv;
        float mm[4] = {};
#pragma unroll
        for (int c = 0; c < 3; ++c) {
            float4 o = make_float4((cen[c][h][0] + cj[0]) * INV_DIV,
                                   (cen[c][h][1] + cj[1]) * INV_DIV,
                                   (cen[c][h][2] + cj[2]) * INV_DIV,
                                   (cen[c][h][3] + cj[3]) * INV_DIV);
            *(float4*)(qkb + ((size_t)(c * 8 + h) << 18)) = o;
#pragma unroll
            for (int j = 0; j < 4; ++j) mm[j] += cen[c][h][j];
        }
#pragma unroll
        for (int j = 0; j < 4; ++j) {
            float gv = gelu_exact((mm[j] * (1.f / 3.f) + cj[j]) * INV_DIV);
            gql[h * 1024 + ii * 32 + j4 + j] = gv;
        }
    }
    __syncthreads();

    // epilogue 2: out2[pos][0..127] = gq[pos] . Wpr + bpr, coalesced writes
    const int pq = tid & 31, pg = tid >> 5;
    float4 wv[8];
#pragma unroll
    for (int h = 0; h < 8; ++h) wv[h] = *(const float4*)&Wpr[h * 128 + pq * 4];
    const float4 bv = *(const float4*)&bpr[pq * 4];

    for (int it = 0; it < 128; ++it) {
        int pos = it * 8 + pg;
        float g8[8];
#pragma unroll
        for (int h = 0; h < 8; ++h) g8[h] = gql[h * 1024 + pos];
        float4 o = bv;
        o.x += g8[0]*wv[0].x + g8[1]*wv[1].x + g8[2]*wv[2].x + g8[3]*wv[3].x
             + g8[4]*wv[4].x + g8[5]*wv[5].x + g8[6]*wv[6].x + g8[7]*wv[7].x;
        o.y += g8[0]*wv[0].y + g8[1]*wv[1].y + g8[2]*wv[2].y + g8[3]*wv[3].y
             + g8[4]*wv[4].y + g8[5]*wv[5].y + g8[6]*wv[6].y + g8[7]*wv[7].y;
        o.z += g8[0]*wv[0].z + g8[1]*wv[1].z + g8[2]*wv[2].z + g8[3]*wv[3].z
             + g8[4]*wv[4].z + g8[5]*wv[5].z + g8[6]*wv[6].z + g8[7]*wv[7].z;
        o.w += g8[0]*wv[0].w + g8[1]*wv[1].w + g8[2]*wv[2].w + g8[3]*wv[3].w
             + g8[4]*wv[4].w + g8[5]*wv[5].w + g8[6]*wv[6].w + g8[7]*wv[7].w;
        int oi = i0 + (pos >> 5), oj = j0 + (pos & 31);
        *(float4*)&out2[(((size_t)(b * 512 + oi) << 9) + oj) * 128 + pq * 4] = o;
    }
}

// ---------------------------------------------------------------------------
// K6: softmax + P@V + sigmoid(gate).  Two-stage reduce (81 shfl vs 144).
// grid=768.
// ---------------------------------------------------------------------------
__global__ __launch_bounds__(256) void k_softmax_pv(
    const float* __restrict__ qk, const float* __restrict__ v, const float* __restrict__ gate,
    float* __restrict__ houts)
{
    __shared__ float Vl[512 * 28];   // 57.3 KB
    const int tid = threadIdx.x;
    const int bch = blockIdx.x >> 4, itile = blockIdx.x & 15;
    const float* vp = v + (size_t)bch * (512 * 24);
    for (int idx = tid; idx < 512 * 24; idx += 256) {
        int j = idx / 24, d = idx - j * 24;
        Vl[j * 28 + d] = vp[idx];
    }
    __syncthreads();

    const int wid = tid >> 6, lane = tid & 63;
    const int b = bch / 24, c = (bch % 24) >> 3, h = bch & 7;
    const int tg = lane >> 3;          // d-trio group 0..7
    for (int rr = 0; rr < 8; ++rr) {
        const int i = itile * 32 + wid * 8 + rr;
        const float* row = qk + ((size_t)bch * 512 + i) * 512;
        float e[8]; float mx = -1e30f;
#pragma unroll
        for (int u = 0; u < 8; ++u) { e[u] = row[lane + 64 * u]; mx = fmaxf(mx, e[u]); }
#pragma unroll
        for (int o = 32; o; o >>= 1) mx = fmaxf(mx, __shfl_xor(mx, o));
        float s = 0.f;
#pragma unroll
        for (int u = 0; u < 8; ++u) { e[u] = __expf(e[u] - mx); s += e[u]; }
#pragma unroll
        for (int o = 32; o; o >>= 1) s += __shfl_xor(s, o);
        float inv = 1.f / s;

        float4 a4[6] = {};
#pragma unroll
        for (int u = 0; u < 8; ++u) {
            float p = e[u] * inv;
            const float* vr = &Vl[(u * 64 + lane) * 28];
#pragma unroll
            for (int k = 0; k < 6; ++k) {
                float4 vv = *(const float4*)(vr + 4 * k);
                a4[k].x = fmaf(p, vv.x, a4[k].x);
                a4[k].y = fmaf(p, vv.y, a4[k].y);
                a4[k].z = fmaf(p, vv.z, a4[k].z);
                a4[k].w = fmaf(p, vv.w, a4[k].w);
            }
        }
        // stage 1: reduce over lane bits 3,4,5 -> class (lane&7) partials
#pragma unroll
        for (int k = 0; k < 6; ++k) {
            a4[k].x += __shfl_xor(a4[k].x, 8);  a4[k].y += __shfl_xor(a4[k].y, 8);
            a4[k].z += __shfl_xor(a4[k].z, 8);  a4[k].w += __shfl_xor(a4[k].w, 8);
            a4[k].x += __shfl_xor(a4[k].x, 16); a4[k].y += __shfl_xor(a4[k].y, 16);
            a4[k].z += __shfl_xor(a4[k].z, 16); a4[k].w += __shfl_xor(a4[k].w, 16);
            a4[k].x += __shfl_xor(a4[k].x, 32); a4[k].y += __shfl_xor(a4[k].y, 32);
            a4[k].z += __shfl_xor(a4[k].z, 32); a4[k].w += __shfl_xor(a4[k].w, 32);
        }
        // stage 2: lane selects d-trio tg, reduce across classes (bits 0..2)
        const float af[24] = {
            a4[0].x, a4[0].y, a4[0].z, a4[0].w, a4[1].x, a4[1].y, a4[1].z, a4[1].w,
            a4[2].x, a4[2].y, a4[2].z, a4[2].w, a4[3].x, a4[3].y, a4[3].z, a4[3].w,
            a4[4].x, a4[4].y, a4[4].z, a4[4].w, a4[5].x, a4[5].y, a4[5].z, a4[5].w };
        float w0 = tg==0?af[0]:tg==1?af[3]:tg==2?af[6]:tg==3?af[9]:tg==4?af[12]:tg==5?af[15]:tg==6?af[18]:af[21];
        float w1 = tg==0?af[1]:tg==1?af[4]:tg==2?af[7]:tg==3?af[10]:tg==4?af[13]:tg==5?af[16]:tg==6?af[19]:af[22];
        float w2 = tg==0?af[2]:tg==1?af[5]:tg==2?af[8]:tg==3?af[11]:tg==4?af[14]:tg==5?af[17]:tg==6?af[20]:af[23];
#pragma unroll
        for (int o = 1; o < 8; o <<= 1) {
            w0 += __shfl_xor(w0, o);
            w1 += __shfl_xor(w1, o);
            w2 += __shfl_xor(w2, o);
        }
        if ((lane & 7) == 0) {
            const int d0 = tg * 3;
            const float* gp = gate + ((size_t)bch * 512 + i) * 24 + d0;
            float* op = houts + ((size_t)(b * 512 + i)) * 576 + c * 192 + h * 24 + d0;
            op[0] = w0 / (1.f + __expf(-gp[0]));
            op[1] = w1 / (1.f + __expf(-gp[1]));
            op[2] = w2 / (1.f + __expf(-gp[2]));
        }
    }
}

// ---------------------------------------------------------------------------
// K7: out1 = houts @ Wo + bo + x*g.  Tiled GEMM: 32x64 tile, BK=32, grid=288.
// ---------------------------------------------------------------------------
__global__ __launch_bounds__(256) void k_out1(
    const float* __restrict__ houts, const float* __restrict__ Wo, const float* __restrict__ bo,
    const float* __restrict__ x, const float* __restrict__ gsc,
    float* __restrict__ out1)
{
    __shared__ float As[32 * 33];
    __shared__ float Bs[32 * 64];
    const int tid = threadIdx.x;
    const int mt = blockIdx.x / 9, nt = blockIdx.x % 9;
    const int m0 = mt * 32, n0 = nt * 64;
    const int tn = tid & 15, tm = tid >> 4;
    float acc[2][4] = {};

    for (int kk = 0; kk < 576; kk += 32) {
        {
            int idx = tid;
#pragma unroll
            for (int i = 0; i < 4; ++i, idx += 256) {
                int k2 = idx & 31, m = idx >> 5;
                As[m * 33 + k2] = houts[(size_t)(m0 + m) * 576 + kk + k2];
            }
        }
        {
            int idx = tid;
#pragma unroll
            for (int i = 0; i < 8; ++i, idx += 256) {
                int n = idx & 63, k2 = idx >> 6;
                Bs[k2 * 64 + n] = Wo[(size_t)(kk + k2) * 576 + n0 + n];
            }
        }
        __syncthreads();
#pragma unroll
        for (int k2 = 0; k2 < 32; ++k2) {
            float a0 = As[(tm * 2 + 0) * 33 + k2];
            float a1 = As[(tm * 2 + 1) * 33 + k2];
            const float4 bv = *(const float4*)&Bs[k2 * 64 + tn * 4];
            acc[0][0] += a0 * bv.x; acc[0][1] += a0 * bv.y; acc[0][2] += a0 * bv.z; acc[0][3] += a0 * bv.w;
            acc[1][0] += a1 * bv.x; acc[1][1] += a1 * bv.y; acc[1][2] += a1 * bv.z; acc[1][3] += a1 * bv.w;
        }
        __syncthreads();
    }

    const float gv = gsc[0];
    const float4 b4 = *(const float4*)&bo[n0 + tn * 4];
#pragma unroll
    for (int r = 0; r < 2; ++r) {
        size_t row = (size_t)m0 + tm * 2 + r;
        size_t off = row * 576 + n0 + tn * 4;
        const float4 x4 = *(const float4*)&x[off];
        float4 o;
        o.x = acc[r][0] + b4.x + x4.x * gv;
        o.y = acc[r][1] + b4.y + x4.y * gv;
        o.z = acc[r][2] + b4.z + x4.z * gv;
        o.w = acc[r][3] + b4.w + x4.w * gv;
        *(float4*)&out1[off] = o;
    }
}

// ---------------------------------------------------------------------------
extern "C" void kernel_launch(void* const* d_in, const int* in_sizes, int n_in,
                              void* d_out, int out_size, void* d_ws, size_t ws_size,
                              hipStream_t stream) {
    const float* x     = (const float*)d_in[0];
    const float* pairX = (const float*)d_in[1];
    const float* g     = (const float*)d_in[2];
    const float* ln1w  = (const float*)d_in[3];
    const float* ln1b  = (const float*)d_in[4];
    const float* ln2w  = (const float*)d_in[5];
    const float* ln2b  = (const float*)d_in[6];
    const float* Wq    = (const float*)d_in[7];
    const float* bq    = (const float*)d_in[8];
    const float* Wk    = (const float*)d_in[9];
    const float* bk    = (const float*)d_in[10];
    const float* Wv    = (const float*)d_in[11];
    const float* bv    = (const float*)d_in[12];
    const float* Wg    = (const float*)d_in[13];
    const float* bg    = (const float*)d_in[14];
    const float* convW = (const float*)d_in[15];
    const float* convB = (const float*)d_in[16];
    const float* Wp    = (const float*)d_in[17];
    const float* bp    = (const float*)d_in[18];
    const float* Wpr   = (const float*)d_in[19];
    const float* bpr   = (const float*)d_in[20];
    const float* Wo    = (const float*)d_in[21];
    const float* bo    = (const float*)d_in[22];

    float* ws   = (float*)d_ws;
    float* q    = ws + OFF_Q;
    float* k    = ws + OFF_K;
    float* vv   = ws + OFF_V;
    float* gt   = ws + OFF_G;
    float* bias = ws + OFF_BIAS;
    float* ori  = ws + OFF_ORI;
    float* qkb  = ws + OFF_QK;
    float* xn   = ws + OFF_XN;     // alias onto qk region (dead until k_conv)
    float* hout = ws + OFF_H;
    float* wph  = ws + OFF_WPH;
    float* csum = ws + OFF_CS;

    float* out1 = (float*)d_out;
    float* out2 = out1 + 589824;

    k_prep<<<dim3(1), dim3(256), 0, stream>>>(ln2w, ln2b, Wp, bp, wph, csum);
    k_ln<<<dim3(256), dim3(256), 0, stream>>>(x, ln1w, ln1b, xn);
    k_proj<<<dim3(192), dim3(256), 0, stream>>>(xn, Wq, bq, Wk, bk, Wv, bv, Wg, bg,
                                                q, k, vv, gt);
    k_pairbias<<<dim3(2048), dim3(256), 0, stream>>>(pairX, wph, csum, bias);
    k_qkmat<<<dim3(768), dim3(256), 0, stream>>>(q, k, bias, ori);
    k_conv<<<dim3(512), dim3(256), 0, stream>>>(ori, convW, convB, Wpr, bpr, qkb, out2);
    k_softmax_pv<<<dim3(768), dim3(256), 0, stream>>>(qkb, vv, gt, hout);
    k_out1<<<dim3(288), dim3(256), 0, stream>>>(hout, Wo, bo, x, g, out1);
}